// Round 2
// 258.344 us; speedup vs baseline: 1.0827x; 1.0827x over previous
//
#include <hip/hip_runtime.h>
#include <hip/hip_bf16.h>
#include <hip/hip_fp16.h>

typedef unsigned int   uint;
typedef unsigned short ushort;

#define NB   8
#define NC   64
#define LL   32768
#define KK   5
#define NG   4
#define NDG  2
#define NGD  8        // NG*NDG
#define NCD  8        // NC / NGD
#define NOFF 40       // NGD*KK
#define DWK  7
#define XROW (LL + 16)   // xT row stride in positions (8 guard slots each side)

typedef _Float16 f16x8 __attribute__((ext_vector_type(8)));
typedef float    f32x4 __attribute__((ext_vector_type(4)));

__device__ __forceinline__ float bf2f(ushort u) {
  union { uint u; float f; } v; v.u = ((uint)u) << 16; return v.f;
}
__device__ __forceinline__ ushort f2bf(float f) {   // round-to-nearest-even
  union { float f; uint u; } v; v.f = f;
  uint r = (v.u + 0x7fffu + ((v.u >> 16) & 1u)) >> 16;
  return (ushort)r;
}
__device__ __forceinline__ uint pkrtz(float a, float b) {
  typedef __fp16 fp16x2n __attribute__((ext_vector_type(2)));
  fp16x2n h = __builtin_amdgcn_cvt_pkrtz(a, b);
  union { fp16x2n h; uint u; } v; v.h = h; return v.u;
}

// ---------------------------------------------------------------------------
// k_prep: permute f32 weights into MAC-friendly layouts.
//  wtA[c*40+o] = pw_off_w[o,c]   wtM[c*40+o] = pw_m_w[o,c]
//  Wf: main conv weight in f16 MFMA A-fragment order for 16x16x32:
//    Wf[((g*3 + t)*64 + lane)*8 + j] = W[o = lane&15][kq = t*32 + (lane>>4)*8 + j]
//    with kidx mapping kq = ktap*8 + c, ktap = d*5 + kh  (zero-pad kq >= 80).
// ---------------------------------------------------------------------------
__global__ __launch_bounds__(256) void k_prep(
    const float* __restrict__ pwA, const float* __restrict__ pwM,
    const float* __restrict__ mw,
    float* __restrict__ wtA, float* __restrict__ wtM, ushort* __restrict__ Wf)
{
  int idx = blockIdx.x * 256 + threadIdx.x;
  if (idx < 2560) {
    int c = idx / 40, o = idx % 40;
    wtA[idx] = pwA[o * NC + c];
  } else if (idx < 5120) {
    int j = idx - 2560;
    int c = j / 40, o = j % 40;
    wtM[j] = pwM[o * NC + c];
  } else if (idx < 11264) {
    int j  = idx - 5120;          // [0, 6144)
    int jj = j & 7;
    int l  = (j >> 3) & 63;
    int gt = j >> 9;              // [0,12)
    int t  = gt % 3, g = gt / 3;
    int o  = l & 15;
    int kq = t * 32 + ((l >> 4) << 3) + jj;
    float val = 0.f;
    if (kq < 80) {
      int ktap = kq >> 3, c = kq & 7;
      int d = ktap / 5, kh = ktap % 5;
      val = mw[((g * 16 + o) * 16 + d * 8 + c) * KK + kh];
    }
    Wf[j] = __half_as_ushort(__float2half(val));
  }
}

// ---------------------------------------------------------------------------
// k_conv: ONE x pass. Depthwise conv7 for both branches -> raw y (bf16) +
// exact f32 row stats (sum, sumsq per branch). One block per (b,c) row.
// GN application is deferred (folded into pointwise weights by k_fin).
// ---------------------------------------------------------------------------
__device__ __forceinline__ void load8f(float* dst, const float* __restrict__ row,
                                       int start)
{
  if (start >= 0 && start + 8 <= LL) {
    float4 a = *(const float4*)(row + start);
    float4 b = *(const float4*)(row + start + 4);
    dst[0] = a.x; dst[1] = a.y; dst[2] = a.z; dst[3] = a.w;
    dst[4] = b.x; dst[5] = b.y; dst[6] = b.z; dst[7] = b.w;
  } else {
#pragma unroll
    for (int j = 0; j < 8; ++j) {
      int p = start + j;
      dst[j] = (p >= 0 && p < LL) ? row[p] : 0.f;
    }
  }
}

__global__ __launch_bounds__(256) void k_conv(
    const float* __restrict__ x,
    const float* __restrict__ dwAw, const float* __restrict__ dwAb,
    const float* __restrict__ dwMw, const float* __restrict__ dwMb,
    ushort* __restrict__ yA, ushort* __restrict__ yM,
    float4* __restrict__ partial)
{
  int tid = threadIdx.x;
  int bc  = blockIdx.x;           // b*64 + c
  int c   = bc & 63;
  const float* row = x + (size_t)bc * LL;

  float wa[DWK], wm[DWK];
#pragma unroll
  for (int j = 0; j < DWK; ++j) {
    wa[j] = dwAw[c * DWK + j];
    wm[j] = dwMw[c * DWK + j];
  }
  float ba = dwAb[c], bm = dwMb[c];

  ushort* oA = yA + (size_t)bc * LL;
  ushort* oM = yM + (size_t)bc * LL;

  float sa = 0.f, qa = 0.f, sm = 0.f, qm = 0.f;
  for (int it = 0; it < 16; ++it) {
    int m = it * 256 + tid;       // chunk index [0,4096)
    int lb = m * 8;
    float v[24];
    load8f(v + 0,  row, lb - 8);
    load8f(v + 8,  row, lb);
    load8f(v + 16, row, lb + 8);
    uint4 pA, pM;
    ushort* ppA = (ushort*)&pA;
    ushort* ppM = (ushort*)&pM;
#pragma unroll
    for (int u = 0; u < 8; ++u) {
      float ya = ba, ym = bm;
#pragma unroll
      for (int j = 0; j < DWK; ++j) {
        float xv = v[5 + u + j];  // x[lb+u-3+j]
        ya += wa[j] * xv;
        ym += wm[j] * xv;
      }
      sa += ya; qa += ya * ya;
      sm += ym; qm += ym * ym;
      ppA[u] = f2bf(ya);
      ppM[u] = f2bf(ym);
    }
    *(uint4*)(oA + lb) = pA;
    *(uint4*)(oM + lb) = pM;
  }

  __shared__ float4 red[256];
  red[tid] = make_float4(sa, qa, sm, qm);
  __syncthreads();
  for (int s = 128; s > 0; s >>= 1) {
    if (tid < s) {
      float4 a = red[tid], b = red[tid + s];
      red[tid] = make_float4(a.x + b.x, a.y + b.y, a.z + b.z, a.w + b.w);
    }
    __syncthreads();
  }
  if (tid == 0) partial[bc] = red[0];
}

// ---------------------------------------------------------------------------
// k_fin: per batch b, fold GN affine (and the x4 offset scale) into the
// pointwise weights/biases:  wAf[b,c,o] = 4*wtA[c,o]*gaA(b,c),
// bAf[b,o] = 4*(pbA[o] + sum_c wtA[c,o]*caA(b,c));  same for M (scale 1).
// Grid: 8 blocks (one per b) x 256 threads.
// ---------------------------------------------------------------------------
__global__ __launch_bounds__(256) void k_fin(
    const float4* __restrict__ partial,
    const float* __restrict__ gnAw, const float* __restrict__ gnAb,
    const float* __restrict__ gnMw, const float* __restrict__ gnMb,
    const float* __restrict__ wtA, const float* __restrict__ wtM,
    const float* __restrict__ pbA, const float* __restrict__ pbM,
    float* __restrict__ wAf, float* __restrict__ wMf,
    float* __restrict__ bAf, float* __restrict__ bMf)
{
  __shared__ float gA[64], cA[64], gM[64], cM[64];
  int b = blockIdx.x;
  int t = threadIdx.x;
  if (t < 64) {
    float4 v = partial[b * 64 + t];
    float mua = v.x / LL, vara = v.y / LL - mua * mua;
    float mum = v.z / LL, varm = v.w / LL - mum * mum;
    float ga = gnAw[t] * rsqrtf(vara + 1e-5f);
    float gm = gnMw[t] * rsqrtf(varm + 1e-5f);
    gA[t] = ga; cA[t] = gnAb[t] - mua * ga;
    gM[t] = gm; cM[t] = gnMb[t] - mum * gm;
  }
  __syncthreads();
  for (int idx = t; idx < 2560; idx += 256) {
    int c = idx / 40;
    wAf[b * 2560 + idx] = 4.f * wtA[idx] * gA[c];
    wMf[b * 2560 + idx] = wtM[idx] * gM[c];
  }
  if (t < 40) {
    float sA = 0.f, sM = 0.f;
    for (int c = 0; c < 64; ++c) {
      sA += wtA[c * 40 + t] * cA[c];
      sM += wtM[c * 40 + t] * cM[c];
    }
    bAf[b * 40 + t] = 4.f * (pbA[t] + sA);
    bMf[b * 40 + t] = pbM[t] + sM;
  }
}

// ---------------------------------------------------------------------------
// k_point: 40x64 matvec per position for both branches using per-b folded
// weights (GN pre-applied). Writes offs f32, attn f16 (softmaxed).
// ---------------------------------------------------------------------------
__device__ __forceinline__ void stage_matvec40(
    const ushort* __restrict__ ysrc,   // y + b*64*LL + l0
    const float* __restrict__ wt,      // [c][40] folded f32
    const float* __restrict__ pb,      // folded bias [40]
    ushort* hs, int tid, float* acc)
{
#pragma unroll
  for (int i = 0; i < 8; ++i) {
    int fid = i * 256 + tid;
    int c = fid >> 5, q = fid & 31;
    ((uint4*)hs)[fid] = *(const uint4*)(ysrc + (size_t)c * LL + q * 8);
  }
  __syncthreads();
#pragma unroll
  for (int o = 0; o < NOFF; ++o) acc[o] = pb[o];
  for (int c = 0; c < NC; ++c) {
    float hv = bf2f(hs[(c << 8) + tid]);
    const float* wr = wt + c * NOFF;
#pragma unroll
    for (int o4 = 0; o4 < 10; ++o4) {
      float4 w = *(const float4*)(wr + (o4 << 2));
      acc[(o4 << 2) + 0] += w.x * hv;
      acc[(o4 << 2) + 1] += w.y * hv;
      acc[(o4 << 2) + 2] += w.z * hv;
      acc[(o4 << 2) + 3] += w.w * hv;
    }
  }
}

__global__ __launch_bounds__(256) void k_point(
    const ushort* __restrict__ yA, const ushort* __restrict__ yM,
    const float* __restrict__ wAf, const float* __restrict__ wMf,
    const float* __restrict__ bAf, const float* __restrict__ bMf,
    float* __restrict__ offs, ushort* __restrict__ attnB)
{
  __shared__ __align__(16) ushort hs[NC * 256];   // 32 KB
  int tid = threadIdx.x;
  int b   = blockIdx.x >> 7;
  int l0  = (blockIdx.x & 127) << 8;
  int l   = l0 + tid;
  float acc[NOFF];

  // ---- offset branch (x4 folded in) ----
  stage_matvec40(yA + (size_t)b * NC * LL + l0, wAf + b * 2560, bAf + b * 40,
                 hs, tid, acc);
  {
    float* op = offs + (size_t)b * NOFF * LL + l;
#pragma unroll
    for (int o = 0; o < NOFF; ++o) op[(size_t)o * LL] = acc[o];
  }
  __syncthreads();   // everyone done reading hs before restage

  // ---- mask branch + softmax ----
  stage_matvec40(yM + (size_t)b * NC * LL + l0, wMf + b * 2560, bMf + b * 40,
                 hs, tid, acc);
  {
    ushort* ap = attnB + (size_t)b * NOFF * LL + l;
#pragma unroll
    for (int g8 = 0; g8 < NGD; ++g8) {
      float mx = acc[g8 * 5];
#pragma unroll
      for (int j = 1; j < 5; ++j) mx = fmaxf(mx, acc[g8 * 5 + j]);
      float e[5]; float s = 0.f;
#pragma unroll
      for (int j = 0; j < 5; ++j) { e[j] = __expf(acc[g8 * 5 + j] - mx); s += e[j]; }
      float r = 1.f / s;
#pragma unroll
      for (int j = 0; j < 5; ++j)
        ap[(size_t)(g8 * 5 + j) * LL] =
            __half_as_ushort(__float2half(e[j] * r));
    }
  }
}

// ---------------------------------------------------------------------------
// k_xpose: x (b,c,l) f32 -> xT (b, gd, slot, 8) f16: one tap gather = 16 B.
// Row stride XROW = LL+16 with 8 zeroed guard slots each side so k_deform
// needs no bounds predication (p clamped to [-1, LL] maps into guards).
// ---------------------------------------------------------------------------
__global__ __launch_bounds__(256) void k_xpose(
    const float* __restrict__ x, ushort* __restrict__ xT)
{
  __shared__ __align__(16) float tile[8 * 256];
  int tid  = threadIdx.x;
  int lblk = blockIdx.x & 127;
  int l0   = lblk << 8;
  int gd   = (blockIdx.x >> 7) & 7;
  int b    = blockIdx.x >> 10;
  const float* src = x + (size_t)(b * NC + gd * 8) * LL + l0;
#pragma unroll
  for (int i = 0; i < 2; ++i) {
    int fid = i * 256 + tid;          // 512 float4 = 8 rows x 64 float4
    int c = fid >> 6, q = fid & 63;
    *(float4*)(tile + c * 256 + q * 4) =
        *(const float4*)(src + (size_t)c * LL + q * 4);
  }
  __syncthreads();
  uint4 pk;
  pk.x = pkrtz(tile[0 * 256 + tid], tile[1 * 256 + tid]);
  pk.y = pkrtz(tile[2 * 256 + tid], tile[3 * 256 + tid]);
  pk.z = pkrtz(tile[4 * 256 + tid], tile[5 * 256 + tid]);
  pk.w = pkrtz(tile[6 * 256 + tid], tile[7 * 256 + tid]);
  size_t rowbase = (size_t)(b * NGD + gd) * (size_t)XROW;
  *(uint4*)(xT + (rowbase + 8 + (size_t)(l0 + tid)) * 8) = pk;
  if (tid < 8) {
    uint4 z = {0, 0, 0, 0};
    if (lblk == 0)   *(uint4*)(xT + (rowbase + tid) * 8) = z;
    if (lblk == 127) *(uint4*)(xT + (rowbase + 8 + LL + tid) * 8) = z;
  }
}

// ---------------------------------------------------------------------------
// k_deform: gather (16B f16) + packed-f16 lerp*attn -> per-wave LDS tile
// S[96 kidx][64 n] -> 12x mfma_f32_16x16x32_f16 against prepped W frags.
// Per-wave private LDS region: no barriers. XOR swizzle (n&7)<<4 on byte
// addresses keeps both ds_write_b128 (per-n) and ds_read_b128 (per-k-slice)
// spread across all 8 16B bank slots.
//   writer: lane n, tap ktap: bytes [n*192 + ktap*16, +16) ^ mask(n)
//   reader: lane l, kstep t, nblk: n = nblk*16+(l&15),
//           bytes [n*192 + t*64 + (l>>4)*16, +16) ^ mask(n); mask(n)=(l&7)<<4
// One block = (b, g, 256 l); each wave owns 64 positions, 16 out channels.
// ---------------------------------------------------------------------------
__global__ __launch_bounds__(256) void k_deform(
    const ushort* __restrict__ xT, const float* __restrict__ offs,
    const ushort* __restrict__ attnH, const ushort* __restrict__ Wf,
    const float* __restrict__ bias, float* __restrict__ out)
{
  __shared__ __align__(16) char S[4 * 12288];   // 48 KB, 12 KB per wave
  int tid  = threadIdx.x;
  int wav  = tid >> 6;
  int lane = tid & 63;
  int lblk = blockIdx.x & 127;
  int g    = (blockIdx.x >> 7) & 3;
  int b    = blockIdx.x >> 9;
  int l    = (lblk << 8) + tid;

  // A-operand fragments: W[o = lane&15][k = t*32 + (lane>>4)*8 + j]
  f16x8 af[3];
#pragma unroll
  for (int t = 0; t < 3; ++t) {
    union { uint4 u; f16x8 h; } cv;
    cv.u = ((const uint4*)Wf)[(g * 3 + t) * 64 + lane];
    af[t] = cv.h;
  }

  // C/D layout: col = lane&15, row = (lane>>4)*4 + reg. Init acc with bias.
  int orow = (lane >> 4) << 2;
  float4 b4 = *(const float4*)(bias + g * 16 + orow);
  f32x4 acc[4];
#pragma unroll
  for (int nb = 0; nb < 4; ++nb) {
    acc[nb][0] = b4.x; acc[nb][1] = b4.y; acc[nb][2] = b4.z; acc[nb][3] = b4.w;
  }

  char* sb  = S + wav * 12288;
  int nbase = lane * 192;           // 96 f16 per row
  int msk   = (lane & 7) << 4;      // swizzle mask (== (n&7)<<4 for both roles)

  // zero the K-pad (kidx 80..95)
  {
    f16x8 Z = {};
    *(f16x8*)(sb + ((nbase + 160) ^ msk)) = Z;
    *(f16x8*)(sb + ((nbase + 176) ^ msk)) = Z;
  }

  const float*  offp = offs  + (size_t)b * NOFF * LL + l;
  const ushort* attp = attnH + (size_t)b * NOFF * LL + l;

#pragma unroll
  for (int d = 0; d < NDG; ++d) {
    const ushort* xr = xT + (size_t)(b * NGD + g * 2 + d) * (size_t)XROW * 8;
#pragma unroll
    for (int kh = 0; kh < KK; ++kh) {
      int ch = (g * 2 + d) * KK + kh;
      float off = offp[(size_t)ch * LL];
      float at  = __half2float(__ushort_as_half(attp[(size_t)ch * LL]));
      float p   = (float)(l - 2 + kh) + off;
      // clamp into guard range; invalid taps hit zeroed guards or w1==0,
      // exactly matching the reference's validity masking.
      p = fminf(fmaxf(p, -1.f), 32768.f);
      float p0f = floorf(p);
      float w1  = p - p0f;
      int   i0  = (int)p0f;
      float f0 = (1.f - w1) * at;
      float f1 = w1 * at;
      _Float16 a0 = (_Float16)f0;
      _Float16 a1 = (_Float16)f1;
      f16x8 F0 = {a0, a0, a0, a0, a0, a0, a0, a0};
      f16x8 F1 = {a1, a1, a1, a1, a1, a1, a1, a1};
      const ushort* q = xr + (size_t)(i0 + 8) * 8;
      f16x8 X0 = *(const f16x8*)q;
      f16x8 X1 = *(const f16x8*)(q + 8);
      f16x8 S8 = X0 * F0 + X1 * F1;     // v_pk_mul/fma_f16
      *(f16x8*)(sb + ((nbase + (d * KK + kh) * 16) ^ msk)) = S8;
    }
  }

  // MFMA: acc[16 o][64 n] += W[16][96] x S[96][64]
  int rb0 = (lane & 15) * 192 + ((lane >> 4) << 4);
#pragma unroll
  for (int nb = 0; nb < 4; ++nb) {
#pragma unroll
    for (int t = 0; t < 3; ++t) {
      f16x8 bf = *(const f16x8*)(sb + ((rb0 + nb * 3072 + t * 64) ^ msk));
      acc[nb] = __builtin_amdgcn_mfma_f32_16x16x32_f16(af[t], bf, acc[nb],
                                                       0, 0, 0);
    }
  }

  float* ob = out + (size_t)(b * NC + g * 16 + orow) * LL
              + (size_t)((lblk << 8) + (wav << 6) + (lane & 15));
#pragma unroll
  for (int nb = 0; nb < 4; ++nb) {
#pragma unroll
    for (int r = 0; r < 4; ++r)
      ob[(size_t)r * LL + (nb << 4)] = acc[nb][r];
  }
}

// ---------------------------------------------------------------------------
extern "C" void kernel_launch(void* const* d_in, const int* in_sizes, int n_in,
                              void* d_out, int out_size, void* d_ws, size_t ws_size,
                              hipStream_t stream)
{
  const float* x    = (const float*)d_in[0];
  const float* dwAw = (const float*)d_in[1];
  const float* dwAb = (const float*)d_in[2];
  const float* gnAw = (const float*)d_in[3];
  const float* gnAb = (const float*)d_in[4];
  const float* pwAw = (const float*)d_in[5];
  const float* pwAb = (const float*)d_in[6];
  const float* dwMw = (const float*)d_in[7];
  const float* dwMb = (const float*)d_in[8];
  const float* gnMw = (const float*)d_in[9];
  const float* gnMb = (const float*)d_in[10];
  const float* pwMw = (const float*)d_in[11];
  const float* pwMb = (const float*)d_in[12];
  const float* mw   = (const float*)d_in[13];
  const float* bias = (const float*)d_in[14];
  float* out = (float*)d_out;

  // ws layout (~130.5 MB peak):
  //  wt/wf/bias/partial ~0.21 MB | yA 33.5 | yM 33.5 | offs 41.9 | attn 21
  //  xT (f16, 33.6 MB incl guards) aliases yA(+yM head) after k_point.
  float* wtA = (float*)d_ws;                     // 2560
  float* wtM = wtA + 2560;                       // 2560
  ushort* Wf = (ushort*)(wtM + 2560);            // 6144 ushort (12 KB)
  float* wAf = (float*)(Wf + 6144);              // 8*2560
  float* wMf = wAf + 20480;                      // 8*2560
  float* bAf = wMf + 20480;                      // 8*40
  float* bMf = bAf + 320;                        // 8*40
  float4* partial = (float4*)(bMf + 320);        // 512 float4
  ushort* yA = (ushort*)(partial + 512);         // 16.78M ushort
  ushort* yM = yA + (size_t)NB * NC * LL;        // 16.78M ushort
  float* offs = (float*)(yM + (size_t)NB * NC * LL);   // 10.49M f32
  ushort* attnB = (ushort*)(offs + (size_t)NB * NOFF * LL); // 10.49M ushort
  ushort* xT = yA;   // y dead after k_point; xT = 64*(LL+16)*8 us, fits yA+yM

  hipLaunchKernelGGL(k_prep, dim3(44), dim3(256), 0, stream,
                     pwAw, pwMw, mw, wtA, wtM, Wf);
  hipLaunchKernelGGL(k_conv, dim3(NB * NC), dim3(256), 0, stream,
                     x, dwAw, dwAb, dwMw, dwMb, yA, yM, partial);
  hipLaunchKernelGGL(k_fin, dim3(NB), dim3(256), 0, stream,
                     partial, gnAw, gnAb, gnMw, gnMb, wtA, wtM, pwAb, pwMb,
                     wAf, wMf, bAf, bMf);
  hipLaunchKernelGGL(k_point, dim3(NB * (LL / 256)), dim3(256), 0, stream,
                     yA, yM, wAf, wMf, bAf, bMf, offs, attnB);
  hipLaunchKernelGGL(k_xpose, dim3(NB * NGD * (LL / 256)), dim3(256), 0, stream,
                     x, xT);
  hipLaunchKernelGGL(k_deform, dim3(NB * NG * (LL / 256)), dim3(256), 0, stream,
                     xT, offs, attnB, Wf, bias, out);
}

// Round 3
// 242.442 us; speedup vs baseline: 1.1537x; 1.0656x over previous
//
#include <hip/hip_runtime.h>
#include <hip/hip_bf16.h>
#include <hip/hip_fp16.h>

typedef unsigned int   uint;
typedef unsigned short ushort;

#define NB   8
#define NC   64
#define LL   32768
#define KK   5
#define NG   4
#define NDG  2
#define NGD  8        // NG*NDG
#define NCD  8        // NC / NGD
#define NOFF 40       // NGD*KK
#define DWK  7
#define XROW (LL + 16)   // xT row stride in positions (8 guard slots each side)

typedef _Float16 f16x8 __attribute__((ext_vector_type(8)));
typedef float    f32x4 __attribute__((ext_vector_type(4)));

__device__ __forceinline__ float bf2f(ushort u) {
  union { uint u; float f; } v; v.u = ((uint)u) << 16; return v.f;
}
__device__ __forceinline__ ushort f2bf(float f) {   // round-to-nearest-even
  union { float f; uint u; } v; v.f = f;
  uint r = (v.u + 0x7fffu + ((v.u >> 16) & 1u)) >> 16;
  return (ushort)r;
}
__device__ __forceinline__ uint pkrtz(float a, float b) {
  typedef __fp16 fp16x2n __attribute__((ext_vector_type(2)));
  fp16x2n h = __builtin_amdgcn_cvt_pkrtz(a, b);
  union { fp16x2n h; uint u; } v; v.h = h; return v.u;
}

// ---------------------------------------------------------------------------
// k_prep: permute f32 weights into MAC-friendly layouts.
//  wtA[c*40+o] = pw_off_w[o,c]   wtM[c*40+o] = pw_m_w[o,c]
//  Wf: main conv weight in f16 MFMA A-fragment order for 16x16x32:
//    Wf[((g*3 + t)*64 + lane)*8 + j] = W[o = lane&15][kq = t*32 + (lane>>4)*8 + j]
//    with kidx mapping kq = ktap*8 + c, ktap = d*5 + kh  (zero-pad kq >= 80).
// ---------------------------------------------------------------------------
__global__ __launch_bounds__(256) void k_prep(
    const float* __restrict__ pwA, const float* __restrict__ pwM,
    const float* __restrict__ mw,
    float* __restrict__ wtA, float* __restrict__ wtM, ushort* __restrict__ Wf)
{
  int idx = blockIdx.x * 256 + threadIdx.x;
  if (idx < 2560) {
    int c = idx / 40, o = idx % 40;
    wtA[idx] = pwA[o * NC + c];
  } else if (idx < 5120) {
    int j = idx - 2560;
    int c = j / 40, o = j % 40;
    wtM[j] = pwM[o * NC + c];
  } else if (idx < 11264) {
    int j  = idx - 5120;          // [0, 6144)
    int jj = j & 7;
    int l  = (j >> 3) & 63;
    int gt = j >> 9;              // [0,12)
    int t  = gt % 3, g = gt / 3;
    int o  = l & 15;
    int kq = t * 32 + ((l >> 4) << 3) + jj;
    float val = 0.f;
    if (kq < 80) {
      int ktap = kq >> 3, c = kq & 7;
      int d = ktap / 5, kh = ktap % 5;
      val = mw[((g * 16 + o) * 16 + d * 8 + c) * KK + kh];
    }
    Wf[j] = __half_as_ushort(__float2half(val));
  }
}

// ---------------------------------------------------------------------------
// k_conv (templated): depthwise conv7 for both branches, 8 channels (one gd
// group) x 256 positions per block -> grid NB*NGD*128 = 8192 blocks (16x the
// old 512: fixes the 16% occupancy / latency-bound profile).
// Per-channel partial stats (sum,sumsq x 2 branches) via 32-lane butterfly ->
// partial[(b*64+c)*128 + lblk]; k_fin reduces the 128 chunks (deterministic).
// WITH_XT=1 additionally emits xT (raw x as f16, (b,gd,slot,8ch) layout) from
// the already-loaded x values, replacing the separate k_xpose pass.
// ---------------------------------------------------------------------------
__device__ __forceinline__ void load8f(float* dst, const float* __restrict__ row,
                                       int start)
{
  if (start >= 0 && start + 8 <= LL) {
    float4 a = *(const float4*)(row + start);
    float4 b = *(const float4*)(row + start + 4);
    dst[0] = a.x; dst[1] = a.y; dst[2] = a.z; dst[3] = a.w;
    dst[4] = b.x; dst[5] = b.y; dst[6] = b.z; dst[7] = b.w;
  } else {
#pragma unroll
    for (int j = 0; j < 8; ++j) {
      int p = start + j;
      dst[j] = (p >= 0 && p < LL) ? row[p] : 0.f;
    }
  }
}

template<int WITH_XT>
__global__ __launch_bounds__(256) void k_conv(
    const float* __restrict__ x,
    const float* __restrict__ dwAw, const float* __restrict__ dwAb,
    const float* __restrict__ dwMw, const float* __restrict__ dwMb,
    ushort* __restrict__ yA, ushort* __restrict__ yM,
    ushort* __restrict__ xT, float4* __restrict__ partial)
{
  __shared__ __align__(16) ushort lx[8 * 256];   // raw x f16 tile [c][pos]
  int tid  = threadIdx.x;
  int lblk = blockIdx.x & 127;
  int gd   = (blockIdx.x >> 7) & 7;
  int b    = blockIdx.x >> 10;
  int c    = tid >> 5;          // channel within gd group (0..7)
  int q    = tid & 31;          // 8-position chunk within 256
  int l0   = lblk << 8;
  int lb   = l0 + q * 8;
  int ch   = gd * 8 + c;
  const float* row = x + (size_t)(b * NC + ch) * LL;

  float v[24];
  load8f(v + 0,  row, lb - 8);
  load8f(v + 8,  row, lb);
  load8f(v + 16, row, lb + 8);

  if (WITH_XT) {
    uint4 xr;
    xr.x = pkrtz(v[8],  v[9]);
    xr.y = pkrtz(v[10], v[11]);
    xr.z = pkrtz(v[12], v[13]);
    xr.w = pkrtz(v[14], v[15]);
    *(uint4*)(lx + c * 256 + q * 8) = xr;
  }

  float wa[DWK], wm[DWK];
#pragma unroll
  for (int j = 0; j < DWK; ++j) {
    wa[j] = dwAw[ch * DWK + j];
    wm[j] = dwMw[ch * DWK + j];
  }
  float ba = dwAb[ch], bm = dwMb[ch];

  float sa = 0.f, qa = 0.f, sm = 0.f, qm = 0.f;
  uint4 pA, pM;
  ushort* ppA = (ushort*)&pA;
  ushort* ppM = (ushort*)&pM;
#pragma unroll
  for (int u = 0; u < 8; ++u) {
    float ya = ba, ym = bm;
#pragma unroll
    for (int j = 0; j < DWK; ++j) {
      float xv = v[5 + u + j];  // x[lb+u-3+j]
      ya += wa[j] * xv;
      ym += wm[j] * xv;
    }
    sa += ya; qa += ya * ya;
    sm += ym; qm += ym * ym;
    ppA[u] = f2bf(ya);
    ppM[u] = f2bf(ym);
  }
  *(uint4*)(yA + (size_t)(b * NC + ch) * LL + lb) = pA;
  *(uint4*)(yM + (size_t)(b * NC + ch) * LL + lb) = pM;

  // butterfly reduce over the 32 lanes sharing this channel
#pragma unroll
  for (int m = 1; m < 32; m <<= 1) {
    sa += __shfl_xor(sa, m);
    qa += __shfl_xor(qa, m);
    sm += __shfl_xor(sm, m);
    qm += __shfl_xor(qm, m);
  }
  if (q == 0)
    partial[((size_t)(b * NC + ch) << 7) + lblk] = make_float4(sa, qa, sm, qm);

  if (WITH_XT) {
    __syncthreads();
    uint4 pk;
    pk.x = (uint)lx[0 * 256 + tid] | ((uint)lx[1 * 256 + tid] << 16);
    pk.y = (uint)lx[2 * 256 + tid] | ((uint)lx[3 * 256 + tid] << 16);
    pk.z = (uint)lx[4 * 256 + tid] | ((uint)lx[5 * 256 + tid] << 16);
    pk.w = (uint)lx[6 * 256 + tid] | ((uint)lx[7 * 256 + tid] << 16);
    size_t rowbase = (size_t)(b * NGD + gd) * (size_t)XROW;
    *(uint4*)(xT + (rowbase + 8 + (size_t)(l0 + tid)) * 8) = pk;
    if (tid < 8) {
      uint4 z = {0, 0, 0, 0};
      if (lblk == 0)   *(uint4*)(xT + (rowbase + tid) * 8) = z;
      if (lblk == 127) *(uint4*)(xT + (rowbase + 8 + LL + tid) * 8) = z;
    }
  }
}

// ---------------------------------------------------------------------------
// k_fin: reduce the 128 per-chunk stat partials per channel, then fold GN
// affine (and the x4 offset scale) into the pointwise weights/biases:
//  wAf[b,c,o] = 4*wtA[c,o]*gaA(b,c),
//  bAf[b,o] = 4*(pbA[o] + sum_c wtA[c,o]*caA(b,c));  same for M (scale 1).
// Grid: 8 blocks (one per b) x 256 threads.
// ---------------------------------------------------------------------------
__global__ __launch_bounds__(256) void k_fin(
    const float4* __restrict__ partial,
    const float* __restrict__ gnAw, const float* __restrict__ gnAb,
    const float* __restrict__ gnMw, const float* __restrict__ gnMb,
    const float* __restrict__ wtA, const float* __restrict__ wtM,
    const float* __restrict__ pbA, const float* __restrict__ pbM,
    float* __restrict__ wAf, float* __restrict__ wMf,
    float* __restrict__ bAf, float* __restrict__ bMf)
{
  __shared__ float4 pr[256];
  __shared__ float gA[64], cA[64], gM[64], cM[64];
  int b = blockIdx.x;
  int t = threadIdx.x;
  {
    int c = t & 63, seg = t >> 6;
    const float4* pp = partial + ((size_t)(b * NC + c) << 7);
    float4 s = make_float4(0.f, 0.f, 0.f, 0.f);
    for (int i = seg; i < 128; i += 4) {
      float4 u = pp[i];
      s.x += u.x; s.y += u.y; s.z += u.z; s.w += u.w;
    }
    pr[t] = s;
  }
  __syncthreads();
  if (t < 64) {
    float4 a0 = pr[t], a1 = pr[t + 64], a2 = pr[t + 128], a3 = pr[t + 192];
    float sx = a0.x + a1.x + a2.x + a3.x;
    float sy = a0.y + a1.y + a2.y + a3.y;
    float sz = a0.z + a1.z + a2.z + a3.z;
    float sw = a0.w + a1.w + a2.w + a3.w;
    float mua = sx / LL, vara = sy / LL - mua * mua;
    float mum = sz / LL, varm = sw / LL - mum * mum;
    float ga = gnAw[t] * rsqrtf(vara + 1e-5f);
    float gm = gnMw[t] * rsqrtf(varm + 1e-5f);
    gA[t] = ga; cA[t] = gnAb[t] - mua * ga;
    gM[t] = gm; cM[t] = gnMb[t] - mum * gm;
  }
  __syncthreads();
  for (int idx = t; idx < 2560; idx += 256) {
    int c = idx / 40;
    wAf[b * 2560 + idx] = 4.f * wtA[idx] * gA[c];
    wMf[b * 2560 + idx] = wtM[idx] * gM[c];
  }
  if (t < 40) {
    float sA = 0.f, sM = 0.f;
    for (int c = 0; c < 64; ++c) {
      sA += wtA[c * 40 + t] * cA[c];
      sM += wtM[c * 40 + t] * cM[c];
    }
    bAf[b * 40 + t] = 4.f * (pbA[t] + sA);
    bMf[b * 40 + t] = pbM[t] + sM;
  }
}

// ---------------------------------------------------------------------------
// k_point: 40x64 matvec per position for both branches using per-b folded
// weights (GN pre-applied). Writes offs f32, attn f16 (softmaxed).
// ---------------------------------------------------------------------------
__device__ __forceinline__ void stage_matvec40(
    const ushort* __restrict__ ysrc,   // y + b*64*LL + l0
    const float* __restrict__ wt,      // [c][40] folded f32
    const float* __restrict__ pb,      // folded bias [40]
    ushort* hs, int tid, float* acc)
{
#pragma unroll
  for (int i = 0; i < 8; ++i) {
    int fid = i * 256 + tid;
    int c = fid >> 5, q = fid & 31;
    ((uint4*)hs)[fid] = *(const uint4*)(ysrc + (size_t)c * LL + q * 8);
  }
  __syncthreads();
#pragma unroll
  for (int o = 0; o < NOFF; ++o) acc[o] = pb[o];
  for (int c = 0; c < NC; ++c) {
    float hv = bf2f(hs[(c << 8) + tid]);
    const float* wr = wt + c * NOFF;
#pragma unroll
    for (int o4 = 0; o4 < 10; ++o4) {
      float4 w = *(const float4*)(wr + (o4 << 2));
      acc[(o4 << 2) + 0] += w.x * hv;
      acc[(o4 << 2) + 1] += w.y * hv;
      acc[(o4 << 2) + 2] += w.z * hv;
      acc[(o4 << 2) + 3] += w.w * hv;
    }
  }
}

__global__ __launch_bounds__(256) void k_point(
    const ushort* __restrict__ yA, const ushort* __restrict__ yM,
    const float* __restrict__ wAf, const float* __restrict__ wMf,
    const float* __restrict__ bAf, const float* __restrict__ bMf,
    float* __restrict__ offs, ushort* __restrict__ attnB)
{
  __shared__ __align__(16) ushort hs[NC * 256];   // 32 KB
  int tid = threadIdx.x;
  int b   = blockIdx.x >> 7;
  int l0  = (blockIdx.x & 127) << 8;
  int l   = l0 + tid;
  float acc[NOFF];

  // ---- offset branch (x4 folded in) ----
  stage_matvec40(yA + (size_t)b * NC * LL + l0, wAf + b * 2560, bAf + b * 40,
                 hs, tid, acc);
  {
    float* op = offs + (size_t)b * NOFF * LL + l;
#pragma unroll
    for (int o = 0; o < NOFF; ++o) op[(size_t)o * LL] = acc[o];
  }
  __syncthreads();   // everyone done reading hs before restage

  // ---- mask branch + softmax ----
  stage_matvec40(yM + (size_t)b * NC * LL + l0, wMf + b * 2560, bMf + b * 40,
                 hs, tid, acc);
  {
    ushort* ap = attnB + (size_t)b * NOFF * LL + l;
#pragma unroll
    for (int g8 = 0; g8 < NGD; ++g8) {
      float mx = acc[g8 * 5];
#pragma unroll
      for (int j = 1; j < 5; ++j) mx = fmaxf(mx, acc[g8 * 5 + j]);
      float e[5]; float s = 0.f;
#pragma unroll
      for (int j = 0; j < 5; ++j) { e[j] = __expf(acc[g8 * 5 + j] - mx); s += e[j]; }
      float r = 1.f / s;
#pragma unroll
      for (int j = 0; j < 5; ++j)
        ap[(size_t)(g8 * 5 + j) * LL] =
            __half_as_ushort(__float2half(e[j] * r));
    }
  }
}

// ---------------------------------------------------------------------------
// k_xpose (fallback path only): x (b,c,l) f32 -> xT (b, gd, slot, 8) f16.
// ---------------------------------------------------------------------------
__global__ __launch_bounds__(256) void k_xpose(
    const float* __restrict__ x, ushort* __restrict__ xT)
{
  __shared__ __align__(16) float tile[8 * 256];
  int tid  = threadIdx.x;
  int lblk = blockIdx.x & 127;
  int l0   = lblk << 8;
  int gd   = (blockIdx.x >> 7) & 7;
  int b    = blockIdx.x >> 10;
  const float* src = x + (size_t)(b * NC + gd * 8) * LL + l0;
#pragma unroll
  for (int i = 0; i < 2; ++i) {
    int fid = i * 256 + tid;          // 512 float4 = 8 rows x 64 float4
    int c = fid >> 6, q = fid & 63;
    *(float4*)(tile + c * 256 + q * 4) =
        *(const float4*)(src + (size_t)c * LL + q * 4);
  }
  __syncthreads();
  uint4 pk;
  pk.x = pkrtz(tile[0 * 256 + tid], tile[1 * 256 + tid]);
  pk.y = pkrtz(tile[2 * 256 + tid], tile[3 * 256 + tid]);
  pk.z = pkrtz(tile[4 * 256 + tid], tile[5 * 256 + tid]);
  pk.w = pkrtz(tile[6 * 256 + tid], tile[7 * 256 + tid]);
  size_t rowbase = (size_t)(b * NGD + gd) * (size_t)XROW;
  *(uint4*)(xT + (rowbase + 8 + (size_t)(l0 + tid)) * 8) = pk;
  if (tid < 8) {
    uint4 z = {0, 0, 0, 0};
    if (lblk == 0)   *(uint4*)(xT + (rowbase + tid) * 8) = z;
    if (lblk == 127) *(uint4*)(xT + (rowbase + 8 + LL + tid) * 8) = z;
  }
}

// ---------------------------------------------------------------------------
// k_deform: gather (16B f16) + packed-f16 lerp*attn -> per-wave LDS tile
// S[96 kidx][64 n] -> 12x mfma_f32_16x16x32_f16 against prepped W frags.
// Per-wave private LDS region: no barriers. XOR swizzle (n&7)<<4 keeps both
// ds_write_b128 (per-n) and ds_read_b128 (per-k-slice) conflict-free.
// One block = (b, g, 256 l); each wave owns 64 positions, 16 out channels.
// ---------------------------------------------------------------------------
__global__ __launch_bounds__(256) void k_deform(
    const ushort* __restrict__ xT, const float* __restrict__ offs,
    const ushort* __restrict__ attnH, const ushort* __restrict__ Wf,
    const float* __restrict__ bias, float* __restrict__ out)
{
  __shared__ __align__(16) char S[4 * 12288];   // 48 KB, 12 KB per wave
  int tid  = threadIdx.x;
  int wav  = tid >> 6;
  int lane = tid & 63;
  int lblk = blockIdx.x & 127;
  int g    = (blockIdx.x >> 7) & 3;
  int b    = blockIdx.x >> 9;
  int l    = (lblk << 8) + tid;

  // A-operand fragments: W[o = lane&15][k = t*32 + (lane>>4)*8 + j]
  f16x8 af[3];
#pragma unroll
  for (int t = 0; t < 3; ++t) {
    union { uint4 u; f16x8 h; } cv;
    cv.u = ((const uint4*)Wf)[(g * 3 + t) * 64 + lane];
    af[t] = cv.h;
  }

  // C/D layout: col = lane&15, row = (lane>>4)*4 + reg. Init acc with bias.
  int orow = (lane >> 4) << 2;
  float4 b4 = *(const float4*)(bias + g * 16 + orow);
  f32x4 acc[4];
#pragma unroll
  for (int nb = 0; nb < 4; ++nb) {
    acc[nb][0] = b4.x; acc[nb][1] = b4.y; acc[nb][2] = b4.z; acc[nb][3] = b4.w;
  }

  char* sb  = S + wav * 12288;
  int nbase = lane * 192;           // 96 f16 per row
  int msk   = (lane & 7) << 4;      // swizzle mask (== (n&7)<<4 for both roles)

  // zero the K-pad (kidx 80..95)
  {
    f16x8 Z = {};
    *(f16x8*)(sb + ((nbase + 160) ^ msk)) = Z;
    *(f16x8*)(sb + ((nbase + 176) ^ msk)) = Z;
  }

  const float*  offp = offs  + (size_t)b * NOFF * LL + l;
  const ushort* attp = attnH + (size_t)b * NOFF * LL + l;

#pragma unroll
  for (int d = 0; d < NDG; ++d) {
    const ushort* xr = xT + (size_t)(b * NGD + g * 2 + d) * (size_t)XROW * 8;
#pragma unroll
    for (int kh = 0; kh < KK; ++kh) {
      int ch = (g * 2 + d) * KK + kh;
      float off = offp[(size_t)ch * LL];
      float at  = __half2float(__ushort_as_half(attp[(size_t)ch * LL]));
      float p   = (float)(l - 2 + kh) + off;
      // clamp into guard range; invalid taps hit zeroed guards or w1==0,
      // exactly matching the reference's validity masking.
      p = fminf(fmaxf(p, -1.f), 32768.f);
      float p0f = floorf(p);
      float w1  = p - p0f;
      int   i0  = (int)p0f;
      float f0 = (1.f - w1) * at;
      float f1 = w1 * at;
      _Float16 a0 = (_Float16)f0;
      _Float16 a1 = (_Float16)f1;
      f16x8 F0 = {a0, a0, a0, a0, a0, a0, a0, a0};
      f16x8 F1 = {a1, a1, a1, a1, a1, a1, a1, a1};
      const ushort* q = xr + (size_t)(i0 + 8) * 8;
      f16x8 X0 = *(const f16x8*)q;
      f16x8 X1 = *(const f16x8*)(q + 8);
      f16x8 S8 = X0 * F0 + X1 * F1;     // v_pk_mul/fma_f16
      *(f16x8*)(sb + ((nbase + (d * KK + kh) * 16) ^ msk)) = S8;
    }
  }

  // MFMA: acc[16 o][64 n] += W[16][96] x S[96][64]
  int rb0 = (lane & 15) * 192 + ((lane >> 4) << 4);
#pragma unroll
  for (int nb = 0; nb < 4; ++nb) {
#pragma unroll
    for (int t = 0; t < 3; ++t) {
      f16x8 bf = *(const f16x8*)(sb + ((rb0 + nb * 3072 + t * 64) ^ msk));
      acc[nb] = __builtin_amdgcn_mfma_f32_16x16x32_f16(af[t], bf, acc[nb],
                                                       0, 0, 0);
    }
  }

  float* ob = out + (size_t)(b * NC + g * 16 + orow) * LL
              + (size_t)((lblk << 8) + (wav << 6) + (lane & 15));
#pragma unroll
  for (int nb = 0; nb < 4; ++nb) {
#pragma unroll
    for (int r = 0; r < 4; ++r)
      ob[(size_t)r * LL + (nb << 4)] = acc[nb][r];
  }
}

// ---------------------------------------------------------------------------
extern "C" void kernel_launch(void* const* d_in, const int* in_sizes, int n_in,
                              void* d_out, int out_size, void* d_ws, size_t ws_size,
                              hipStream_t stream)
{
  const float* x    = (const float*)d_in[0];
  const float* dwAw = (const float*)d_in[1];
  const float* dwAb = (const float*)d_in[2];
  const float* gnAw = (const float*)d_in[3];
  const float* gnAb = (const float*)d_in[4];
  const float* pwAw = (const float*)d_in[5];
  const float* pwAb = (const float*)d_in[6];
  const float* dwMw = (const float*)d_in[7];
  const float* dwMb = (const float*)d_in[8];
  const float* gnMw = (const float*)d_in[9];
  const float* gnMb = (const float*)d_in[10];
  const float* pwMw = (const float*)d_in[11];
  const float* pwMb = (const float*)d_in[12];
  const float* mw   = (const float*)d_in[13];
  const float* bias = (const float*)d_in[14];
  float* out = (float*)d_out;

  // Head (~0.2 MB): weights / folded weights. Then big buffers.
  float* wtA = (float*)d_ws;                     // 2560
  float* wtM = wtA + 2560;                       // 2560
  ushort* Wf = (ushort*)(wtM + 2560);            // 6144 ushort (12 KB)
  float* wAf = (float*)(Wf + 6144);              // 8*2560
  float* wMf = wAf + 20480;                      // 8*2560
  float* bAf = wMf + 20480;                      // 8*40
  float* bMf = bAf + 320;                        // 8*40
  float* headEnd = bMf + 320 + 2048;             // keep old offset for yA
  ushort* yA = (ushort*)headEnd;                 // 16.78M ushort
  ushort* yM = yA + (size_t)NB * NC * LL;        // 16.78M ushort

  const size_t xtElems  = (size_t)NB * NGD * XROW * 8;   // 16.79M ushort
  const size_t offElems = (size_t)NB * NOFF * LL;        // 10.49M

  // Layout A (big ws): y | xT | offs | attn  (k_conv<1> fuses k_xpose).
  // Layout B        : y | offs | attn; xT aliases yA (k_xpose after k_point).
  size_t needA = ((char*)(yM + (size_t)NB * NC * LL) - (char*)d_ws)
               + xtElems * 2 + offElems * 4 + offElems * 2;
  bool bigws = ws_size >= needA;

  ushort* xT;
  float* offs;
  if (bigws) {
    xT   = yM + (size_t)NB * NC * LL;
    offs = (float*)(xT + xtElems);
  } else {
    xT   = yA;                       // y dead after k_point
    offs = (float*)(yM + (size_t)NB * NC * LL);
  }
  ushort* attnB = (ushort*)(offs + offElems);
  // stat partials (1 MB) alias offs: offs is dead until k_point, and k_fin
  // consumes partials before k_point runs.
  float4* partial = (float4*)offs;

  hipLaunchKernelGGL(k_prep, dim3(44), dim3(256), 0, stream,
                     pwAw, pwMw, mw, wtA, wtM, Wf);
  if (bigws) {
    hipLaunchKernelGGL((k_conv<1>), dim3(NB * NGD * 128), dim3(256), 0, stream,
                       x, dwAw, dwAb, dwMw, dwMb, yA, yM, xT, partial);
  } else {
    hipLaunchKernelGGL((k_conv<0>), dim3(NB * NGD * 128), dim3(256), 0, stream,
                       x, dwAw, dwAb, dwMw, dwMb, yA, yM, (ushort*)nullptr,
                       partial);
  }
  hipLaunchKernelGGL(k_fin, dim3(NB), dim3(256), 0, stream,
                     partial, gnAw, gnAb, gnMw, gnMb, wtA, wtM, pwAb, pwMb,
                     wAf, wMf, bAf, bMf);
  hipLaunchKernelGGL(k_point, dim3(NB * (LL / 256)), dim3(256), 0, stream,
                     yA, yM, wAf, wMf, bAf, bMf, offs, attnB);
  if (!bigws) {
    hipLaunchKernelGGL(k_xpose, dim3(NB * NGD * (LL / 256)), dim3(256), 0,
                       stream, x, xT);
  }
  hipLaunchKernelGGL(k_deform, dim3(NB * NG * (LL / 256)), dim3(256), 0, stream,
                     xT, offs, attnB, Wf, bias, out);
}

// Round 4
// 221.037 us; speedup vs baseline: 1.2654x; 1.0968x over previous
//
#include <hip/hip_runtime.h>
#include <hip/hip_bf16.h>
#include <hip/hip_fp16.h>

typedef unsigned int   uint;
typedef unsigned short ushort;

#define NB   8
#define NC   64
#define LL   32768
#define KK   5
#define NG   4
#define NDG  2
#define NGD  8        // NG*NDG
#define NCD  8        // NC / NGD
#define NOFF 40       // NGD*KK
#define DWK  7
#define XROW (LL + 16)   // xT row stride in positions (8 guard slots each side)

typedef _Float16 f16x8 __attribute__((ext_vector_type(8)));
typedef float    f32x4 __attribute__((ext_vector_type(4)));

__device__ __forceinline__ ushort f2bf(float f) {   // round-to-nearest-even
  union { float f; uint u; } v; v.f = f;
  uint r = (v.u + 0x7fffu + ((v.u >> 16) & 1u)) >> 16;
  return (ushort)r;
}
__device__ __forceinline__ uint pkrtz(float a, float b) {
  typedef __fp16 fp16x2n __attribute__((ext_vector_type(2)));
  fp16x2n h = __builtin_amdgcn_cvt_pkrtz(a, b);
  union { fp16x2n h; uint u; } v; v.h = h; return v.u;
}

// ---------------------------------------------------------------------------
// k_prep: permute f32 weights into MAC-friendly layouts.
//  wtA[c*40+o] = pw_off_w[o,c]   wtM[c*40+o] = pw_m_w[o,c]
//  Wf: main conv weight in f16 MFMA A-fragment order for 16x16x32 (k_deform).
// ---------------------------------------------------------------------------
__global__ __launch_bounds__(256) void k_prep(
    const float* __restrict__ pwA, const float* __restrict__ pwM,
    const float* __restrict__ mw,
    float* __restrict__ wtA, float* __restrict__ wtM, ushort* __restrict__ Wf)
{
  int idx = blockIdx.x * 256 + threadIdx.x;
  if (idx < 2560) {
    int c = idx / 40, o = idx % 40;
    wtA[idx] = pwA[o * NC + c];
  } else if (idx < 5120) {
    int j = idx - 2560;
    int c = j / 40, o = j % 40;
    wtM[j] = pwM[o * NC + c];
  } else if (idx < 11264) {
    int j  = idx - 5120;          // [0, 6144)
    int jj = j & 7;
    int l  = (j >> 3) & 63;
    int gt = j >> 9;              // [0,12)
    int t  = gt % 3, g = gt / 3;
    int o  = l & 15;
    int kq = t * 32 + ((l >> 4) << 3) + jj;
    float val = 0.f;
    if (kq < 80) {
      int ktap = kq >> 3, c = kq & 7;
      int d = ktap / 5, kh = ktap % 5;
      val = mw[((g * 16 + o) * 16 + d * 8 + c) * KK + kh];
    }
    Wf[j] = __half_as_ushort(__float2half(val));
  }
}

// ---------------------------------------------------------------------------
// k_conv (templated): depthwise conv7 for both branches, 8 channels x 256
// positions per block, grid 8192. y stored as f16 (pkrtz) for the MFMA
// k_point. Per-channel partial stats via 32-lane butterfly.
// WITH_XT=1 additionally emits xT (raw x as f16) replacing k_xpose.
// ---------------------------------------------------------------------------
__device__ __forceinline__ void load8f(float* dst, const float* __restrict__ row,
                                       int start)
{
  if (start >= 0 && start + 8 <= LL) {
    float4 a = *(const float4*)(row + start);
    float4 b = *(const float4*)(row + start + 4);
    dst[0] = a.x; dst[1] = a.y; dst[2] = a.z; dst[3] = a.w;
    dst[4] = b.x; dst[5] = b.y; dst[6] = b.z; dst[7] = b.w;
  } else {
#pragma unroll
    for (int j = 0; j < 8; ++j) {
      int p = start + j;
      dst[j] = (p >= 0 && p < LL) ? row[p] : 0.f;
    }
  }
}

template<int WITH_XT>
__global__ __launch_bounds__(256) void k_conv(
    const float* __restrict__ x,
    const float* __restrict__ dwAw, const float* __restrict__ dwAb,
    const float* __restrict__ dwMw, const float* __restrict__ dwMb,
    ushort* __restrict__ yA, ushort* __restrict__ yM,
    ushort* __restrict__ xT, float4* __restrict__ partial)
{
  __shared__ __align__(16) ushort lx[8 * 256];   // raw x f16 tile [c][pos]
  int tid  = threadIdx.x;
  int lblk = blockIdx.x & 127;
  int gd   = (blockIdx.x >> 7) & 7;
  int b    = blockIdx.x >> 10;
  int c    = tid >> 5;          // channel within gd group (0..7)
  int q    = tid & 31;          // 8-position chunk within 256
  int l0   = lblk << 8;
  int lb   = l0 + q * 8;
  int ch   = gd * 8 + c;
  const float* row = x + (size_t)(b * NC + ch) * LL;

  float v[24];
  load8f(v + 0,  row, lb - 8);
  load8f(v + 8,  row, lb);
  load8f(v + 16, row, lb + 8);

  if (WITH_XT) {
    uint4 xr;
    xr.x = pkrtz(v[8],  v[9]);
    xr.y = pkrtz(v[10], v[11]);
    xr.z = pkrtz(v[12], v[13]);
    xr.w = pkrtz(v[14], v[15]);
    *(uint4*)(lx + c * 256 + q * 8) = xr;
  }

  float wa[DWK], wm[DWK];
#pragma unroll
  for (int j = 0; j < DWK; ++j) {
    wa[j] = dwAw[ch * DWK + j];
    wm[j] = dwMw[ch * DWK + j];
  }
  float ba = dwAb[ch], bm = dwMb[ch];

  float sa = 0.f, qa = 0.f, sm = 0.f, qm = 0.f;
  float ya8[8], ym8[8];
#pragma unroll
  for (int u = 0; u < 8; ++u) {
    float ya = ba, ym = bm;
#pragma unroll
    for (int j = 0; j < DWK; ++j) {
      float xv = v[5 + u + j];  // x[lb+u-3+j]
      ya += wa[j] * xv;
      ym += wm[j] * xv;
    }
    sa += ya; qa += ya * ya;
    sm += ym; qm += ym * ym;
    ya8[u] = ya; ym8[u] = ym;
  }
  uint4 pA, pM;
  pA.x = pkrtz(ya8[0], ya8[1]); pA.y = pkrtz(ya8[2], ya8[3]);
  pA.z = pkrtz(ya8[4], ya8[5]); pA.w = pkrtz(ya8[6], ya8[7]);
  pM.x = pkrtz(ym8[0], ym8[1]); pM.y = pkrtz(ym8[2], ym8[3]);
  pM.z = pkrtz(ym8[4], ym8[5]); pM.w = pkrtz(ym8[6], ym8[7]);
  *(uint4*)(yA + (size_t)(b * NC + ch) * LL + lb) = pA;
  *(uint4*)(yM + (size_t)(b * NC + ch) * LL + lb) = pM;

  // butterfly reduce over the 32 lanes sharing this channel
#pragma unroll
  for (int m = 1; m < 32; m <<= 1) {
    sa += __shfl_xor(sa, m);
    qa += __shfl_xor(qa, m);
    sm += __shfl_xor(sm, m);
    qm += __shfl_xor(qm, m);
  }
  if (q == 0)
    partial[((size_t)(b * NC + ch) << 7) + lblk] = make_float4(sa, qa, sm, qm);

  if (WITH_XT) {
    __syncthreads();
    uint4 pk;
    pk.x = (uint)lx[0 * 256 + tid] | ((uint)lx[1 * 256 + tid] << 16);
    pk.y = (uint)lx[2 * 256 + tid] | ((uint)lx[3 * 256 + tid] << 16);
    pk.z = (uint)lx[4 * 256 + tid] | ((uint)lx[5 * 256 + tid] << 16);
    pk.w = (uint)lx[6 * 256 + tid] | ((uint)lx[7 * 256 + tid] << 16);
    size_t rowbase = (size_t)(b * NGD + gd) * (size_t)XROW;
    *(uint4*)(xT + (rowbase + 8 + (size_t)(l0 + tid)) * 8) = pk;
    if (tid < 8) {
      uint4 z = {0, 0, 0, 0};
      if (lblk == 0)   *(uint4*)(xT + (rowbase + tid) * 8) = z;
      if (lblk == 127) *(uint4*)(xT + (rowbase + 8 + LL + tid) * 8) = z;
    }
  }
}

// ---------------------------------------------------------------------------
// k_fin: reduce the 128 per-chunk stat partials per channel, then emit
// per-batch folded pointwise weights as f16 MFMA A-fragments with the
// softmax-friendly row permutation, plus the 48-row folded bias vectors.
// Row mapping (per 16-row tile t, row m): h = m>>2, s = t*4 + (m&3),
//   o = 10*h + s for s<10, pad (zero) otherwise.  => each D-lane (holding
// rows h*4..h*4+3 of all 3 tiles) owns o = 10h..10h+9 = 2 softmax groups.
// wF[b][br][t][ks][lane][j] = fold(W)[c = ks*32+(lane>>4)*8+j][o(t, lane&15)]
// bias48[b][br][t*16+m] = foldedBias[o(t,m)].
// ---------------------------------------------------------------------------
__global__ __launch_bounds__(256) void k_fin(
    const float4* __restrict__ partial,
    const float* __restrict__ gnAw, const float* __restrict__ gnAb,
    const float* __restrict__ gnMw, const float* __restrict__ gnMb,
    const float* __restrict__ wtA, const float* __restrict__ wtM,
    const float* __restrict__ pbA, const float* __restrict__ pbM,
    ushort* __restrict__ wF, float* __restrict__ bias48)
{
  __shared__ float4 pr[256];
  __shared__ float gA[64], cA[64], gM[64], cM[64];
  __shared__ float sbA[40], sbM[40];
  int b = blockIdx.x;
  int t = threadIdx.x;
  {
    int c = t & 63, seg = t >> 6;
    const float4* pp = partial + ((size_t)(b * NC + c) << 7);
    float4 s = make_float4(0.f, 0.f, 0.f, 0.f);
    for (int i = seg; i < 128; i += 4) {
      float4 u = pp[i];
      s.x += u.x; s.y += u.y; s.z += u.z; s.w += u.w;
    }
    pr[t] = s;
  }
  __syncthreads();
  if (t < 64) {
    float4 a0 = pr[t], a1 = pr[t + 64], a2 = pr[t + 128], a3 = pr[t + 192];
    float sx = a0.x + a1.x + a2.x + a3.x;
    float sy = a0.y + a1.y + a2.y + a3.y;
    float sz = a0.z + a1.z + a2.z + a3.z;
    float sw = a0.w + a1.w + a2.w + a3.w;
    float mua = sx / LL, vara = sy / LL - mua * mua;
    float mum = sz / LL, varm = sw / LL - mum * mum;
    float ga = gnAw[t] * rsqrtf(vara + 1e-5f);
    float gm = gnMw[t] * rsqrtf(varm + 1e-5f);
    gA[t] = ga; cA[t] = gnAb[t] - mua * ga;
    gM[t] = gm; cM[t] = gnMb[t] - mum * gm;
  }
  __syncthreads();
  if (t < 40) {
    float sA = 0.f, sM = 0.f;
    for (int c = 0; c < 64; ++c) {
      sA += wtA[c * 40 + t] * cA[c];
      sM += wtM[c * 40 + t] * cM[c];
    }
    sbA[t] = 4.f * (pbA[t] + sA);
    sbM[t] = pbM[t] + sM;
  }
  // fragment weights (needs gA/gM, already visible)
  for (int idx = t; idx < 6144; idx += 256) {
    int br = idx >= 3072 ? 1 : 0;
    int e  = idx - br * 3072;
    int tt = e >> 10, ks = (e >> 9) & 1, ln = (e >> 3) & 63, j = e & 7;
    int rr = ln & 15, h2 = rr >> 2, s = tt * 4 + (rr & 3);
    int c  = ks * 32 + ((ln >> 4) << 3) + j;
    float v = 0.f;
    if (s < 10) {
      int o = 10 * h2 + s;
      v = br ? wtM[c * 40 + o] * gM[c] : 4.f * wtA[c * 40 + o] * gA[c];
    }
    wF[(size_t)b * 6144 + idx] = __half_as_ushort(__float2half(v));
  }
  __syncthreads();
  if (t < 96) {
    int br  = t >= 48 ? 1 : 0;
    int row = t - br * 48;
    int rr = row & 15, tt = row >> 4;
    int h2 = rr >> 2, s = tt * 4 + (rr & 3);
    float v = 0.f;
    if (s < 10) { int o = 10 * h2 + s; v = br ? sbM[o] : sbA[o]; }
    bias48[b * 96 + t] = v;
  }
}

// ---------------------------------------------------------------------------
// k_point (MFMA): per block (b, 256 pos), both branches:
//   D[40 o][256 l] = Wfold[40][64] x h[64][256]  via 16x16x32 f16 MFMA
// (3 m-tiles x 2 k-steps x 4 n-tiles per wave = 24 MFMA/branch/wave).
// h staged in LDS [c][256 pos] f16 with XOR swizzle on the pos offset:
//   byte = c*512 + ((pos*2) ^ (((c>>3)&3)<<5))
// Staging writes b128 (16B blocks, swizzle preserves them); B-frag gather is
// 8x ds_read_u16 at j*512 stride; the 4 lane-groups (c offsets g*8) map to
// disjoint 8-bank bands via the swizzle -> conflict-free.
// Softmax groups are lane-local thanks to the k_fin row permutation
// (lane h*4.. rows across tiles carry o = 10h..10h+9).
// ---------------------------------------------------------------------------
__global__ __launch_bounds__(256) void k_point(
    const ushort* __restrict__ yA, const ushort* __restrict__ yM,
    const ushort* __restrict__ wF, const float* __restrict__ bias48,
    float* __restrict__ offs, ushort* __restrict__ attnB)
{
  __shared__ __align__(16) char hsB[64 * 512];   // 32 KB
  int tid = threadIdx.x;
  int b   = blockIdx.x >> 7;
  int l0  = (blockIdx.x & 127) << 8;
  int w   = tid >> 6;
  int ln  = tid & 63;
  int h   = ln >> 4;
  int col = ln & 15;
  int msk = h << 5;

  const ushort* wFb = wF + (size_t)b * 6144;
  const float*  bb  = bias48 + b * 96;

  // ================= branch A (offsets, x4 folded) =================
  {
    const ushort* ysrc = yA + (size_t)b * NC * LL + l0;
#pragma unroll
    for (int i = 0; i < 8; ++i) {
      int fid = i * 256 + tid;
      int c = fid >> 5, q = fid & 31;
      *(uint4*)(hsB + c * 512 + ((q << 4) ^ (((c >> 3) & 3) << 5))) =
          *(const uint4*)(ysrc + (size_t)c * LL + q * 8);
    }
    __syncthreads();

    f16x8 af[3][2];
#pragma unroll
    for (int t = 0; t < 3; ++t)
#pragma unroll
      for (int ks = 0; ks < 2; ++ks) {
        union { uint4 u; f16x8 hh; } cv;
        cv.u = ((const uint4*)wFb)[(t * 2 + ks) * 64 + ln];
        af[t][ks] = cv.hh;
      }
    f32x4 acc[3][4];
#pragma unroll
    for (int t = 0; t < 3; ++t) {
      float4 bv = *(const float4*)(bb + t * 16 + h * 4);
#pragma unroll
      for (int nt = 0; nt < 4; ++nt) {
        acc[t][nt][0] = bv.x; acc[t][nt][1] = bv.y;
        acc[t][nt][2] = bv.z; acc[t][nt][3] = bv.w;
      }
    }
#pragma unroll
    for (int nt = 0; nt < 4; ++nt) {
      int pb2 = ((((w * 4 + nt) * 16 + col) * 2) ^ msk);
#pragma unroll
      for (int ks = 0; ks < 2; ++ks) {
        const char* gp = hsB + (ks * 32 + h * 8) * 512 + pb2;
        f16x8 bf;
#pragma unroll
        for (int j = 0; j < 8; ++j)
          bf[j] = *(const _Float16*)(gp + j * 512);
#pragma unroll
        for (int t = 0; t < 3; ++t)
          acc[t][nt] = __builtin_amdgcn_mfma_f32_16x16x32_f16(
              af[t][ks], bf, acc[t][nt], 0, 0, 0);
      }
    }
    float* op = offs + (size_t)b * NOFF * LL + l0 + w * 64 + col;
#pragma unroll
    for (int t = 0; t < 3; ++t)
#pragma unroll
      for (int r = 0; r < 4; ++r) {
        const int s = t * 4 + r;
        if (s >= 10) continue;
#pragma unroll
        for (int nt = 0; nt < 4; ++nt)
          op[(size_t)(10 * h + s) * LL + nt * 16] = acc[t][nt][r];
      }
  }
  __syncthreads();   // everyone done reading hsB before restage

  // ================= branch M (mask + softmax) =================
  {
    const ushort* ysrc = yM + (size_t)b * NC * LL + l0;
#pragma unroll
    for (int i = 0; i < 8; ++i) {
      int fid = i * 256 + tid;
      int c = fid >> 5, q = fid & 31;
      *(uint4*)(hsB + c * 512 + ((q << 4) ^ (((c >> 3) & 3) << 5))) =
          *(const uint4*)(ysrc + (size_t)c * LL + q * 8);
    }
    __syncthreads();

    f16x8 af[3][2];
#pragma unroll
    for (int t = 0; t < 3; ++t)
#pragma unroll
      for (int ks = 0; ks < 2; ++ks) {
        union { uint4 u; f16x8 hh; } cv;
        cv.u = ((const uint4*)(wFb + 3072))[(t * 2 + ks) * 64 + ln];
        af[t][ks] = cv.hh;
      }
    f32x4 acc[3][4];
#pragma unroll
    for (int t = 0; t < 3; ++t) {
      float4 bv = *(const float4*)(bb + 48 + t * 16 + h * 4);
#pragma unroll
      for (int nt = 0; nt < 4; ++nt) {
        acc[t][nt][0] = bv.x; acc[t][nt][1] = bv.y;
        acc[t][nt][2] = bv.z; acc[t][nt][3] = bv.w;
      }
    }
#pragma unroll
    for (int nt = 0; nt < 4; ++nt) {
      int pb2 = ((((w * 4 + nt) * 16 + col) * 2) ^ msk);
#pragma unroll
      for (int ks = 0; ks < 2; ++ks) {
        const char* gp = hsB + (ks * 32 + h * 8) * 512 + pb2;
        f16x8 bf;
#pragma unroll
        for (int j = 0; j < 8; ++j)
          bf[j] = *(const _Float16*)(gp + j * 512);
#pragma unroll
        for (int t = 0; t < 3; ++t)
          acc[t][nt] = __builtin_amdgcn_mfma_f32_16x16x32_f16(
              af[t][ks], bf, acc[t][nt], 0, 0, 0);
      }
    }
    ushort* ap = attnB + (size_t)b * NOFF * LL + l0 + w * 64 + col;
#pragma unroll
    for (int nt = 0; nt < 4; ++nt) {
      float v0[5], v1[5];
#pragma unroll
      for (int s = 0; s < 5; ++s)  v0[s] = acc[s >> 2][nt][s & 3];
#pragma unroll
      for (int s = 5; s < 10; ++s) v1[s - 5] = acc[s >> 2][nt][s & 3];
      float m0 = fmaxf(fmaxf(fmaxf(v0[0], v0[1]), fmaxf(v0[2], v0[3])), v0[4]);
      float m1 = fmaxf(fmaxf(fmaxf(v1[0], v1[1]), fmaxf(v1[2], v1[3])), v1[4]);
      float e0[5], e1[5], s0 = 0.f, s1 = 0.f;
#pragma unroll
      for (int j = 0; j < 5; ++j) { e0[j] = __expf(v0[j] - m0); s0 += e0[j]; }
#pragma unroll
      for (int j = 0; j < 5; ++j) { e1[j] = __expf(v1[j] - m1); s1 += e1[j]; }
      float r0 = 1.f / s0, r1 = 1.f / s1;
#pragma unroll
      for (int j = 0; j < 5; ++j)
        ap[(size_t)(10 * h + j) * LL + nt * 16] =
            __half_as_ushort(__float2half(e0[j] * r0));
#pragma unroll
      for (int j = 0; j < 5; ++j)
        ap[(size_t)(10 * h + 5 + j) * LL + nt * 16] =
            __half_as_ushort(__float2half(e1[j] * r1));
    }
  }
}

// ---------------------------------------------------------------------------
// k_xpose (fallback path only): x (b,c,l) f32 -> xT (b, gd, slot, 8) f16.
// ---------------------------------------------------------------------------
__global__ __launch_bounds__(256) void k_xpose(
    const float* __restrict__ x, ushort* __restrict__ xT)
{
  __shared__ __align__(16) float tile[8 * 256];
  int tid  = threadIdx.x;
  int lblk = blockIdx.x & 127;
  int l0   = lblk << 8;
  int gd   = (blockIdx.x >> 7) & 7;
  int b    = blockIdx.x >> 10;
  const float* src = x + (size_t)(b * NC + gd * 8) * LL + l0;
#pragma unroll
  for (int i = 0; i < 2; ++i) {
    int fid = i * 256 + tid;          // 512 float4 = 8 rows x 64 float4
    int c = fid >> 6, q = fid & 63;
    *(float4*)(tile + c * 256 + q * 4) =
        *(const float4*)(src + (size_t)c * LL + q * 4);
  }
  __syncthreads();
  uint4 pk;
  pk.x = pkrtz(tile[0 * 256 + tid], tile[1 * 256 + tid]);
  pk.y = pkrtz(tile[2 * 256 + tid], tile[3 * 256 + tid]);
  pk.z = pkrtz(tile[4 * 256 + tid], tile[5 * 256 + tid]);
  pk.w = pkrtz(tile[6 * 256 + tid], tile[7 * 256 + tid]);
  size_t rowbase = (size_t)(b * NGD + gd) * (size_t)XROW;
  *(uint4*)(xT + (rowbase + 8 + (size_t)(l0 + tid)) * 8) = pk;
  if (tid < 8) {
    uint4 z = {0, 0, 0, 0};
    if (lblk == 0)   *(uint4*)(xT + (rowbase + tid) * 8) = z;
    if (lblk == 127) *(uint4*)(xT + (rowbase + 8 + LL + tid) * 8) = z;
  }
}

// ---------------------------------------------------------------------------
// k_deform: gather (16B f16) + packed-f16 lerp*attn -> per-wave LDS tile
// S[96 kidx][64 n] -> 12x mfma_f32_16x16x32_f16 against prepped W frags.
// ---------------------------------------------------------------------------
__global__ __launch_bounds__(256) void k_deform(
    const ushort* __restrict__ xT, const float* __restrict__ offs,
    const ushort* __restrict__ attnH, const ushort* __restrict__ Wf,
    const float* __restrict__ bias, float* __restrict__ out)
{
  __shared__ __align__(16) char S[4 * 12288];   // 48 KB, 12 KB per wave
  int tid  = threadIdx.x;
  int wav  = tid >> 6;
  int lane = tid & 63;
  int lblk = blockIdx.x & 127;
  int g    = (blockIdx.x >> 7) & 3;
  int b    = blockIdx.x >> 9;
  int l    = (lblk << 8) + tid;

  // A-operand fragments: W[o = lane&15][k = t*32 + (lane>>4)*8 + j]
  f16x8 af[3];
#pragma unroll
  for (int t = 0; t < 3; ++t) {
    union { uint4 u; f16x8 h; } cv;
    cv.u = ((const uint4*)Wf)[(g * 3 + t) * 64 + lane];
    af[t] = cv.h;
  }

  // C/D layout: col = lane&15, row = (lane>>4)*4 + reg. Init acc with bias.
  int orow = (lane >> 4) << 2;
  float4 b4 = *(const float4*)(bias + g * 16 + orow);
  f32x4 acc[4];
#pragma unroll
  for (int nb = 0; nb < 4; ++nb) {
    acc[nb][0] = b4.x; acc[nb][1] = b4.y; acc[nb][2] = b4.z; acc[nb][3] = b4.w;
  }

  char* sb  = S + wav * 12288;
  int nbase = lane * 192;           // 96 f16 per row
  int msk   = (lane & 7) << 4;      // swizzle mask (== (n&7)<<4 for both roles)

  // zero the K-pad (kidx 80..95)
  {
    f16x8 Z = {};
    *(f16x8*)(sb + ((nbase + 160) ^ msk)) = Z;
    *(f16x8*)(sb + ((nbase + 176) ^ msk)) = Z;
  }

  const float*  offp = offs  + (size_t)b * NOFF * LL + l;
  const ushort* attp = attnH + (size_t)b * NOFF * LL + l;

#pragma unroll
  for (int d = 0; d < NDG; ++d) {
    const ushort* xr = xT + (size_t)(b * NGD + g * 2 + d) * (size_t)XROW * 8;
#pragma unroll
    for (int kh = 0; kh < KK; ++kh) {
      int ch = (g * 2 + d) * KK + kh;
      float off = offp[(size_t)ch * LL];
      float at  = __half2float(__ushort_as_half(attp[(size_t)ch * LL]));
      float p   = (float)(l - 2 + kh) + off;
      // clamp into guard range; invalid taps hit zeroed guards or w1==0,
      // exactly matching the reference's validity masking.
      p = fminf(fmaxf(p, -1.f), 32768.f);
      float p0f = floorf(p);
      float w1  = p - p0f;
      int   i0  = (int)p0f;
      float f0 = (1.f - w1) * at;
      float f1 = w1 * at;
      _Float16 a0 = (_Float16)f0;
      _Float16 a1 = (_Float16)f1;
      f16x8 F0 = {a0, a0, a0, a0, a0, a0, a0, a0};
      f16x8 F1 = {a1, a1, a1, a1, a1, a1, a1, a1};
      const ushort* q = xr + (size_t)(i0 + 8) * 8;
      f16x8 X0 = *(const f16x8*)q;
      f16x8 X1 = *(const f16x8*)(q + 8);
      f16x8 S8 = X0 * F0 + X1 * F1;     // v_pk_mul/fma_f16
      *(f16x8*)(sb + ((nbase + (d * KK + kh) * 16) ^ msk)) = S8;
    }
  }

  // MFMA: acc[16 o][64 n] += W[16][96] x S[96][64]
  int rb0 = (lane & 15) * 192 + ((lane >> 4) << 4);
#pragma unroll
  for (int nb = 0; nb < 4; ++nb) {
#pragma unroll
    for (int t = 0; t < 3; ++t) {
      f16x8 bf = *(const f16x8*)(sb + ((rb0 + nb * 3072 + t * 64) ^ msk));
      acc[nb] = __builtin_amdgcn_mfma_f32_16x16x32_f16(af[t], bf, acc[nb],
                                                       0, 0, 0);
    }
  }

  float* ob = out + (size_t)(b * NC + g * 16 + orow) * LL
              + (size_t)((lblk << 8) + (wav << 6) + (lane & 15));
#pragma unroll
  for (int nb = 0; nb < 4; ++nb) {
#pragma unroll
    for (int r = 0; r < 4; ++r)
      ob[(size_t)r * LL + (nb << 4)] = acc[nb][r];
  }
}

// ---------------------------------------------------------------------------
extern "C" void kernel_launch(void* const* d_in, const int* in_sizes, int n_in,
                              void* d_out, int out_size, void* d_ws, size_t ws_size,
                              hipStream_t stream)
{
  const float* x    = (const float*)d_in[0];
  const float* dwAw = (const float*)d_in[1];
  const float* dwAb = (const float*)d_in[2];
  const float* gnAw = (const float*)d_in[3];
  const float* gnAb = (const float*)d_in[4];
  const float* pwAw = (const float*)d_in[5];
  const float* pwAb = (const float*)d_in[6];
  const float* dwMw = (const float*)d_in[7];
  const float* dwMb = (const float*)d_in[8];
  const float* gnMw = (const float*)d_in[9];
  const float* gnMb = (const float*)d_in[10];
  const float* pwMw = (const float*)d_in[11];
  const float* pwMb = (const float*)d_in[12];
  const float* mw   = (const float*)d_in[13];
  const float* bias = (const float*)d_in[14];
  float* out = (float*)d_out;

  // Head (~131 KB): raw folded weights + fragment weights + biases.
  float* wtA = (float*)d_ws;                     // 2560 f
  float* wtM = wtA + 2560;                       // 2560 f
  ushort* Wf = (ushort*)(wtM + 2560);            // 6144 us (deform frags)
  ushort* wFp = Wf + 6144;                       // 8*6144 us (point frags)
  float* bias48 = (float*)(wFp + 49152);         // 8*96 f
  ushort* yA = (ushort*)(bias48 + 768);          // 16.78M us
  ushort* yM = yA + (size_t)NB * NC * LL;        // 16.78M us

  const size_t xtElems  = (size_t)NB * NGD * XROW * 8;   // 16.79M ushort
  const size_t offElems = (size_t)NB * NOFF * LL;        // 10.49M

  // Layout A (big ws): y | xT | offs | attn  (k_conv<1> fuses k_xpose).
  // Layout B        : y | offs | attn; xT aliases yA (k_xpose after k_point).
  size_t needA = ((char*)(yM + (size_t)NB * NC * LL) - (char*)d_ws)
               + xtElems * 2 + offElems * 4 + offElems * 2;
  bool bigws = ws_size >= needA;

  ushort* xT;
  float* offs;
  if (bigws) {
    xT   = yM + (size_t)NB * NC * LL;
    offs = (float*)(xT + xtElems);
  } else {
    xT   = yA;                       // y dead after k_point
    offs = (float*)(yM + (size_t)NB * NC * LL);
  }
  ushort* attnB = (ushort*)(offs + offElems);
  // stat partials (1 MB) alias offs: offs is dead until k_point, and k_fin
  // consumes partials before k_point runs.
  float4* partial = (float4*)offs;

  hipLaunchKernelGGL(k_prep, dim3(44), dim3(256), 0, stream,
                     pwAw, pwMw, mw, wtA, wtM, Wf);
  if (bigws) {
    hipLaunchKernelGGL((k_conv<1>), dim3(NB * NGD * 128), dim3(256), 0, stream,
                       x, dwAw, dwAb, dwMw, dwMb, yA, yM, xT, partial);
  } else {
    hipLaunchKernelGGL((k_conv<0>), dim3(NB * NGD * 128), dim3(256), 0, stream,
                       x, dwAw, dwAb, dwMw, dwMb, yA, yM, (ushort*)nullptr,
                       partial);
  }
  hipLaunchKernelGGL(k_fin, dim3(NB), dim3(256), 0, stream,
                     partial, gnAw, gnAb, gnMw, gnMb, wtA, wtM, pwAb, pwMb,
                     wFp, bias48);
  hipLaunchKernelGGL(k_point, dim3(NB * (LL / 256)), dim3(256), 0, stream,
                     yA, yM, wFp, bias48, offs, attnB);
  if (!bigws) {
    hipLaunchKernelGGL(k_xpose, dim3(NB * NGD * (LL / 256)), dim3(256), 0,
                       stream, x, xT);
  }
  hipLaunchKernelGGL(k_deform, dim3(NB * NG * (LL / 256)), dim3(256), 0, stream,
                     xT, offs, attnB, Wf, bias, out);
}

// Round 5
// 197.460 us; speedup vs baseline: 1.4165x; 1.1194x over previous
//
#include <hip/hip_runtime.h>
#include <hip/hip_bf16.h>
#include <hip/hip_fp16.h>

typedef unsigned int   uint;
typedef unsigned short ushort;

#define NB   8
#define NC   64
#define LL   32768
#define KK   5
#define NG   4
#define NDG  2
#define NGD  8        // NG*NDG
#define NCD  8        // NC / NGD
#define NOFF 40       // NGD*KK
#define DWK  7
#define XROW (LL + 16)   // xT row stride in positions (8 guard slots each side)

typedef _Float16 f16x8 __attribute__((ext_vector_type(8)));
typedef float    f32x4 __attribute__((ext_vector_type(4)));

__device__ __forceinline__ uint pkrtz(float a, float b) {
  typedef __fp16 fp16x2n __attribute__((ext_vector_type(2)));
  fp16x2n h = __builtin_amdgcn_cvt_pkrtz(a, b);
  union { fp16x2n h; uint u; } v; v.h = h; return v.u;
}

// ---------------------------------------------------------------------------
// k_prep: wtA/wtM raw folded layouts + Wf (deform A-frags, verified layout).
// ---------------------------------------------------------------------------
__global__ __launch_bounds__(256) void k_prep(
    const float* __restrict__ pwA, const float* __restrict__ pwM,
    const float* __restrict__ mw,
    float* __restrict__ wtA, float* __restrict__ wtM, ushort* __restrict__ Wf)
{
  int idx = blockIdx.x * 256 + threadIdx.x;
  if (idx < 2560) {
    int c = idx / 40, o = idx % 40;
    wtA[idx] = pwA[o * NC + c];
  } else if (idx < 5120) {
    int j = idx - 2560;
    int c = j / 40, o = j % 40;
    wtM[j] = pwM[o * NC + c];
  } else if (idx < 11264) {
    int j  = idx - 5120;          // [0, 6144)
    int jj = j & 7;
    int l  = (j >> 3) & 63;
    int gt = j >> 9;              // [0,12)
    int t  = gt % 3, g = gt / 3;
    int o  = l & 15;
    int kq = t * 32 + ((l >> 4) << 3) + jj;
    float val = 0.f;
    if (kq < 80) {
      int ktap = kq >> 3, c = kq & 7;
      int d = ktap / 5, kh = ktap % 5;
      val = mw[((g * 16 + o) * 16 + d * 8 + c) * KK + kh];
    }
    Wf[j] = __half_as_ushort(__float2half(val));
  }
}

// ---------------------------------------------------------------------------
// k_conv: depthwise conv7 both branches, 8 ch x 256 pos per block (grid 8192).
// y stored f16; per-channel partial stats via 32-lane butterfly; also emits
// xT (raw x f16, (b,gd,slot,8ch) with guards) from the loaded x values.
// ---------------------------------------------------------------------------
__device__ __forceinline__ void load8f(float* dst, const float* __restrict__ row,
                                       int start)
{
  if (start >= 0 && start + 8 <= LL) {
    float4 a = *(const float4*)(row + start);
    float4 b = *(const float4*)(row + start + 4);
    dst[0] = a.x; dst[1] = a.y; dst[2] = a.z; dst[3] = a.w;
    dst[4] = b.x; dst[5] = b.y; dst[6] = b.z; dst[7] = b.w;
  } else {
#pragma unroll
    for (int j = 0; j < 8; ++j) {
      int p = start + j;
      dst[j] = (p >= 0 && p < LL) ? row[p] : 0.f;
    }
  }
}

__global__ __launch_bounds__(256) void k_conv(
    const float* __restrict__ x,
    const float* __restrict__ dwAw, const float* __restrict__ dwAb,
    const float* __restrict__ dwMw, const float* __restrict__ dwMb,
    ushort* __restrict__ yA, ushort* __restrict__ yM,
    ushort* __restrict__ xT, float4* __restrict__ partial)
{
  __shared__ __align__(16) ushort lx[8 * 256];   // raw x f16 tile [c][pos]
  int tid  = threadIdx.x;
  int lblk = blockIdx.x & 127;
  int gd   = (blockIdx.x >> 7) & 7;
  int b    = blockIdx.x >> 10;
  int c    = tid >> 5;          // channel within gd group (0..7)
  int q    = tid & 31;          // 8-position chunk within 256
  int l0   = lblk << 8;
  int lb   = l0 + q * 8;
  int ch   = gd * 8 + c;
  const float* row = x + (size_t)(b * NC + ch) * LL;

  float v[24];
  load8f(v + 0,  row, lb - 8);
  load8f(v + 8,  row, lb);
  load8f(v + 16, row, lb + 8);

  {
    uint4 xr;
    xr.x = pkrtz(v[8],  v[9]);
    xr.y = pkrtz(v[10], v[11]);
    xr.z = pkrtz(v[12], v[13]);
    xr.w = pkrtz(v[14], v[15]);
    *(uint4*)(lx + c * 256 + q * 8) = xr;
  }

  float wa[DWK], wm[DWK];
#pragma unroll
  for (int j = 0; j < DWK; ++j) {
    wa[j] = dwAw[ch * DWK + j];
    wm[j] = dwMw[ch * DWK + j];
  }
  float ba = dwAb[ch], bm = dwMb[ch];

  float sa = 0.f, qa = 0.f, sm = 0.f, qm = 0.f;
  float ya8[8], ym8[8];
#pragma unroll
  for (int u = 0; u < 8; ++u) {
    float ya = ba, ym = bm;
#pragma unroll
    for (int j = 0; j < DWK; ++j) {
      float xv = v[5 + u + j];  // x[lb+u-3+j]
      ya += wa[j] * xv;
      ym += wm[j] * xv;
    }
    sa += ya; qa += ya * ya;
    sm += ym; qm += ym * ym;
    ya8[u] = ya; ym8[u] = ym;
  }
  uint4 pA, pM;
  pA.x = pkrtz(ya8[0], ya8[1]); pA.y = pkrtz(ya8[2], ya8[3]);
  pA.z = pkrtz(ya8[4], ya8[5]); pA.w = pkrtz(ya8[6], ya8[7]);
  pM.x = pkrtz(ym8[0], ym8[1]); pM.y = pkrtz(ym8[2], ym8[3]);
  pM.z = pkrtz(ym8[4], ym8[5]); pM.w = pkrtz(ym8[6], ym8[7]);
  *(uint4*)(yA + (size_t)(b * NC + ch) * LL + lb) = pA;
  *(uint4*)(yM + (size_t)(b * NC + ch) * LL + lb) = pM;

  // butterfly reduce over the 32 lanes sharing this channel
#pragma unroll
  for (int m = 1; m < 32; m <<= 1) {
    sa += __shfl_xor(sa, m);
    qa += __shfl_xor(qa, m);
    sm += __shfl_xor(sm, m);
    qm += __shfl_xor(qm, m);
  }
  if (q == 0)
    partial[((size_t)(b * NC + ch) << 7) + lblk] = make_float4(sa, qa, sm, qm);

  __syncthreads();
  {
    uint4 pk;
    pk.x = (uint)lx[0 * 256 + tid] | ((uint)lx[1 * 256 + tid] << 16);
    pk.y = (uint)lx[2 * 256 + tid] | ((uint)lx[3 * 256 + tid] << 16);
    pk.z = (uint)lx[4 * 256 + tid] | ((uint)lx[5 * 256 + tid] << 16);
    pk.w = (uint)lx[6 * 256 + tid] | ((uint)lx[7 * 256 + tid] << 16);
    size_t rowbase = (size_t)(b * NGD + gd) * (size_t)XROW;
    *(uint4*)(xT + (rowbase + 8 + (size_t)(l0 + tid)) * 8) = pk;
    if (tid < 8) {
      uint4 z = {0, 0, 0, 0};
      if (lblk == 0)   *(uint4*)(xT + (rowbase + tid) * 8) = z;
      if (lblk == 127) *(uint4*)(xT + (rowbase + 8 + LL + tid) * 8) = z;
    }
  }
}

// ---------------------------------------------------------------------------
// k_fin: reduce stat partials, fold GN into pointwise weights, emit per-batch
// f16 A-frags with PER-GROUP m-tiles for k_pd:
//   wFp[b][br][g][ks][lane][j] = fold(W)[c = ks*32+(lane>>4)*8+j][o = 10g+(lane&15)]
//   (rows (lane&15) >= 10 are zero pad)
//   biasPt[b][br][g][m] = foldedBias[10g+m] (m<10), else 0.
// ---------------------------------------------------------------------------
__global__ __launch_bounds__(256) void k_fin(
    const float4* __restrict__ partial,
    const float* __restrict__ gnAw, const float* __restrict__ gnAb,
    const float* __restrict__ gnMw, const float* __restrict__ gnMb,
    const float* __restrict__ wtA, const float* __restrict__ wtM,
    const float* __restrict__ pbA, const float* __restrict__ pbM,
    ushort* __restrict__ wFp, float* __restrict__ biasPt)
{
  __shared__ float4 pr[256];
  __shared__ float gA[64], cA[64], gM[64], cM[64];
  __shared__ float sbA[40], sbM[40];
  int b = blockIdx.x;
  int t = threadIdx.x;
  {
    int c = t & 63, seg = t >> 6;
    const float4* pp = partial + ((size_t)(b * NC + c) << 7);
    float4 s = make_float4(0.f, 0.f, 0.f, 0.f);
    for (int i = seg; i < 128; i += 4) {
      float4 u = pp[i];
      s.x += u.x; s.y += u.y; s.z += u.z; s.w += u.w;
    }
    pr[t] = s;
  }
  __syncthreads();
  if (t < 64) {
    float4 a0 = pr[t], a1 = pr[t + 64], a2 = pr[t + 128], a3 = pr[t + 192];
    float sx = a0.x + a1.x + a2.x + a3.x;
    float sy = a0.y + a1.y + a2.y + a3.y;
    float sz = a0.z + a1.z + a2.z + a3.z;
    float sw = a0.w + a1.w + a2.w + a3.w;
    float mua = sx / LL, vara = sy / LL - mua * mua;
    float mum = sz / LL, varm = sw / LL - mum * mum;
    float ga = gnAw[t] * rsqrtf(vara + 1e-5f);
    float gm = gnMw[t] * rsqrtf(varm + 1e-5f);
    gA[t] = ga; cA[t] = gnAb[t] - mua * ga;
    gM[t] = gm; cM[t] = gnMb[t] - mum * gm;
  }
  __syncthreads();
  if (t < 40) {
    float sA = 0.f, sM = 0.f;
    for (int c = 0; c < 64; ++c) {
      sA += wtA[c * 40 + t] * cA[c];
      sM += wtM[c * 40 + t] * cM[c];
    }
    sbA[t] = 4.f * (pbA[t] + sA);
    sbM[t] = pbM[t] + sM;
  }
  // fragment weights (2 br x 4 g x 2 ks x 64 ln x 8 j = 8192)
  for (int idx = t; idx < 8192; idx += 256) {
    int br = idx >> 12;
    int e  = idx & 4095;
    int g  = e >> 10;
    int ks = (e >> 9) & 1;
    int ln = (e >> 3) & 63;
    int j  = e & 7;
    int rr = ln & 15;
    int c  = ks * 32 + ((ln >> 4) << 3) + j;
    float v = 0.f;
    if (rr < 10) {
      int o = 10 * g + rr;
      v = br ? wtM[c * 40 + o] * gM[c] : 4.f * wtA[c * 40 + o] * gA[c];
    }
    wFp[(size_t)b * 8192 + idx] = __half_as_ushort(__float2half(v));
  }
  __syncthreads();
  if (t < 128) {
    int br = t >> 6, g = (t >> 4) & 3, m = t & 15;
    float v = 0.f;
    if (m < 10) v = br ? sbM[10 * g + m] : sbA[10 * g + m];
    biasPt[b * 128 + t] = v;
  }
}

// ---------------------------------------------------------------------------
// k_pd: fused pointwise + softmax + deform over 64-position blocks.
// Phase 1 (point): wave w computes channels 10w..10w+9 (group w) for all 64
//   positions via per-group m-tile MFMAs; hs staged INTERLEAVED
//   (word(c,pos) = yA|yM<<16) at byte c*256 + ((pos*4)^(h(c)<<6)) with
//   h(c) = (c>>3)&3; B-frag = 8 ds_read_b32 stride 256 + v_perm split
//   (bank = col + 16*((nt^h)&1) -> 2-way, free).
// Handoff: lane dumps its 10 (off, logit) f32 into its wave's private S
//   region, rereads per-position (same-wave DS ordering), softmax in f32.
// Phase 2 (deform): verified k_deform body with g = wave id, l = lb0+lane.
// LDS: 48 KB; staging (16 KB) + dumps alias the S-tile region (barrier
// separates hs reads from dumps; dump->reread->S-build are wave-private).
// ---------------------------------------------------------------------------
__global__ __launch_bounds__(256) void k_pd(
    const ushort* __restrict__ yA, const ushort* __restrict__ yM,
    const ushort* __restrict__ xT,
    const ushort* __restrict__ wFp, const float* __restrict__ biasPt,
    const ushort* __restrict__ Wf, const float* __restrict__ bias,
    float* __restrict__ out)
{
  __shared__ __align__(16) char S[4 * 12288];   // 48 KB
  int tid = threadIdx.x;
  int w   = tid >> 6;
  int ln  = tid & 63;
  int h   = ln >> 4;
  int col = ln & 15;
  int b   = blockIdx.x >> 9;
  int lb0 = (blockIdx.x & 511) << 6;

  // ---- stage interleaved h tiles ----
  {
    const ushort* srcA = yA + (size_t)b * NC * LL + lb0;
    const ushort* srcM = yM + (size_t)b * NC * LL + lb0;
#pragma unroll
    for (int i = 0; i < 4; ++i) {
      int fid = i * 256 + tid;          // 1024 = 64 c x 16 qc
      int c = fid >> 4, qc = fid & 15;
      uint2 vA = *(const uint2*)(srcA + (size_t)c * LL + qc * 4);
      uint2 vM = *(const uint2*)(srcM + (size_t)c * LL + qc * 4);
      uint4 wv;
      wv.x = __builtin_amdgcn_perm(vM.x, vA.x, 0x05040100u);
      wv.y = __builtin_amdgcn_perm(vM.x, vA.x, 0x07060302u);
      wv.z = __builtin_amdgcn_perm(vM.y, vA.y, 0x05040100u);
      wv.w = __builtin_amdgcn_perm(vM.y, vA.y, 0x07060302u);
      *(uint4*)(S + c * 256 + ((qc << 4) ^ (((c >> 3) & 3) << 6))) = wv;
    }
  }

  // A-frags + bias (global loads overlap staging)
  const uint4* wFb = (const uint4*)(wFp + (size_t)b * 8192);
  f16x8 afA[2], afM[2];
#pragma unroll
  for (int ks = 0; ks < 2; ++ks) {
    union { uint4 u; f16x8 v; } cvA, cvM;
    cvA.u = wFb[(w * 2 + ks) * 64 + ln];
    cvM.u = wFb[512 + (w * 2 + ks) * 64 + ln];
    afA[ks] = cvA.v; afM[ks] = cvM.v;
  }
  f32x4 accA[4], accM[4];
  {
    float4 bvA = *(const float4*)(biasPt + b * 128 + w * 16 + h * 4);
    float4 bvM = *(const float4*)(biasPt + b * 128 + 64 + w * 16 + h * 4);
#pragma unroll
    for (int nt = 0; nt < 4; ++nt) {
      accA[nt][0]=bvA.x; accA[nt][1]=bvA.y; accA[nt][2]=bvA.z; accA[nt][3]=bvA.w;
      accM[nt][0]=bvM.x; accM[nt][1]=bvM.y; accM[nt][2]=bvM.z; accM[nt][3]=bvM.w;
    }
  }
  __syncthreads();

  // ---- point MFMAs ----
#pragma unroll
  for (int nt = 0; nt < 4; ++nt) {
#pragma unroll
    for (int ks = 0; ks < 2; ++ks) {
      const char* gp = S + (ks * 32 + h * 8) * 256
                     + ((((nt * 16 + col) << 2)) ^ (h << 6));
      uint r0 = *(const uint*)(gp + 0 * 256);
      uint r1 = *(const uint*)(gp + 1 * 256);
      uint r2 = *(const uint*)(gp + 2 * 256);
      uint r3 = *(const uint*)(gp + 3 * 256);
      uint r4 = *(const uint*)(gp + 4 * 256);
      uint r5 = *(const uint*)(gp + 5 * 256);
      uint r6 = *(const uint*)(gp + 6 * 256);
      uint r7 = *(const uint*)(gp + 7 * 256);
      union { uint u[4]; f16x8 v; } bA, bM;
      bA.u[0] = __builtin_amdgcn_perm(r1, r0, 0x05040100u);
      bA.u[1] = __builtin_amdgcn_perm(r3, r2, 0x05040100u);
      bA.u[2] = __builtin_amdgcn_perm(r5, r4, 0x05040100u);
      bA.u[3] = __builtin_amdgcn_perm(r7, r6, 0x05040100u);
      bM.u[0] = __builtin_amdgcn_perm(r1, r0, 0x07060302u);
      bM.u[1] = __builtin_amdgcn_perm(r3, r2, 0x07060302u);
      bM.u[2] = __builtin_amdgcn_perm(r5, r4, 0x07060302u);
      bM.u[3] = __builtin_amdgcn_perm(r7, r6, 0x07060302u);
      accA[nt] = __builtin_amdgcn_mfma_f32_16x16x32_f16(afA[ks], bA.v,
                                                        accA[nt], 0, 0, 0);
      accM[nt] = __builtin_amdgcn_mfma_f32_16x16x32_f16(afM[ks], bM.v,
                                                        accM[nt], 0, 0, 0);
    }
  }
  __syncthreads();   // all waves done reading hs before dumps overwrite it

  // ---- dump (off, logit) into wave-private region, reread per-position ----
  char* wb = S + w * 12288;
#pragma unroll
  for (int r = 0; r < 4; ++r) {
    int s = h * 4 + r;
    if (s < 10) {
#pragma unroll
      for (int nt = 0; nt < 4; ++nt) {
        int pos = nt * 16 + col;
        *(float*)(wb + (s << 8) + (pos << 2)) = accA[nt][r];
        *(float*)(wb + 2560 + (s << 8) + (pos << 2)) = accM[nt][r];
      }
    }
  }
  // same-wave DS ordering guarantees dump visibility for these reads
  float off[10], lg[10];
#pragma unroll
  for (int s = 0; s < 10; ++s) {
    off[s] = *(const float*)(wb + (s << 8) + (ln << 2));
    lg[s]  = *(const float*)(wb + 2560 + (s << 8) + (ln << 2));
  }
  // softmax per 5-tap group, f32 (lane-local)
  float at[10];
  {
    float m0 = fmaxf(fmaxf(fmaxf(lg[0], lg[1]), fmaxf(lg[2], lg[3])), lg[4]);
    float m1 = fmaxf(fmaxf(fmaxf(lg[5], lg[6]), fmaxf(lg[7], lg[8])), lg[9]);
    float e[10], s0 = 0.f, s1 = 0.f;
#pragma unroll
    for (int j = 0; j < 5; ++j) { e[j] = __expf(lg[j] - m0); s0 += e[j]; }
#pragma unroll
    for (int j = 5; j < 10; ++j) { e[j] = __expf(lg[j] - m1); s1 += e[j]; }
    float r0 = 1.f / s0, r1 = 1.f / s1;
#pragma unroll
    for (int j = 0; j < 5; ++j)  at[j] = e[j] * r0;
#pragma unroll
    for (int j = 5; j < 10; ++j) at[j] = e[j] * r1;
  }

  // ---- deform phase: g = wave id, position l = lb0 + ln ----
  int g = w;
  int l = lb0 + ln;

  f16x8 af[3];
#pragma unroll
  for (int t = 0; t < 3; ++t) {
    union { uint4 u; f16x8 hh; } cv;
    cv.u = ((const uint4*)Wf)[(g * 3 + t) * 64 + ln];
    af[t] = cv.hh;
  }
  int orow = (ln >> 4) << 2;
  float4 b4 = *(const float4*)(bias + g * 16 + orow);
  f32x4 acc[4];
#pragma unroll
  for (int nb = 0; nb < 4; ++nb) {
    acc[nb][0] = b4.x; acc[nb][1] = b4.y; acc[nb][2] = b4.z; acc[nb][3] = b4.w;
  }

  char* sb  = wb;                   // wave-private S tile (overwrites dump)
  int nbase = ln * 192;             // 96 f16 per row
  int msk   = (ln & 7) << 4;

  // zero the K-pad (kidx 80..95) -- after the rereads above
  {
    f16x8 Z = {};
    *(f16x8*)(sb + ((nbase + 160) ^ msk)) = Z;
    *(f16x8*)(sb + ((nbase + 176) ^ msk)) = Z;
  }

#pragma unroll
  for (int d = 0; d < NDG; ++d) {
    const ushort* xr = xT + (size_t)(b * NGD + g * 2 + d) * (size_t)XROW * 8;
#pragma unroll
    for (int kh = 0; kh < KK; ++kh) {
      int s = d * KK + kh;
      float p = (float)(l - 2 + kh) + off[s];
      p = fminf(fmaxf(p, -1.f), 32768.f);
      float p0f = floorf(p);
      float w1  = p - p0f;
      int   i0  = (int)p0f;
      float f0 = (1.f - w1) * at[s];
      float f1 = w1 * at[s];
      _Float16 a0 = (_Float16)f0;
      _Float16 a1 = (_Float16)f1;
      f16x8 F0 = {a0, a0, a0, a0, a0, a0, a0, a0};
      f16x8 F1 = {a1, a1, a1, a1, a1, a1, a1, a1};
      const ushort* q = xr + (size_t)(i0 + 8) * 8;
      f16x8 X0 = *(const f16x8*)q;
      f16x8 X1 = *(const f16x8*)(q + 8);
      f16x8 S8 = X0 * F0 + X1 * F1;
      *(f16x8*)(sb + ((nbase + s * 16) ^ msk)) = S8;
    }
  }

  int rb0 = (ln & 15) * 192 + ((ln >> 4) << 4);
#pragma unroll
  for (int nb = 0; nb < 4; ++nb) {
#pragma unroll
    for (int t = 0; t < 3; ++t) {
      f16x8 bf = *(const f16x8*)(sb + ((rb0 + nb * 3072 + t * 64) ^ msk));
      acc[nb] = __builtin_amdgcn_mfma_f32_16x16x32_f16(af[t], bf, acc[nb],
                                                       0, 0, 0);
    }
  }

  float* ob = out + (size_t)(b * NC + g * 16 + orow) * LL + lb0 + (ln & 15);
#pragma unroll
  for (int nb = 0; nb < 4; ++nb) {
#pragma unroll
    for (int r = 0; r < 4; ++r)
      ob[(size_t)r * LL + (nb << 4)] = acc[nb][r];
  }
}

// ---------------------------------------------------------------------------
extern "C" void kernel_launch(void* const* d_in, const int* in_sizes, int n_in,
                              void* d_out, int out_size, void* d_ws, size_t ws_size,
                              hipStream_t stream)
{
  const float* x    = (const float*)d_in[0];
  const float* dwAw = (const float*)d_in[1];
  const float* dwAb = (const float*)d_in[2];
  const float* gnAw = (const float*)d_in[3];
  const float* gnAb = (const float*)d_in[4];
  const float* pwAw = (const float*)d_in[5];
  const float* pwAb = (const float*)d_in[6];
  const float* dwMw = (const float*)d_in[7];
  const float* dwMb = (const float*)d_in[8];
  const float* gnMw = (const float*)d_in[9];
  const float* gnMb = (const float*)d_in[10];
  const float* pwMw = (const float*)d_in[11];
  const float* pwMb = (const float*)d_in[12];
  const float* mw   = (const float*)d_in[13];
  const float* bias = (const float*)d_in[14];
  float* out = (float*)d_out;

  // Workspace (~102 MB total; prior rounds proved >=164 MB available):
  float* wtA = (float*)d_ws;                       // 2560 f
  float* wtM = wtA + 2560;                         // 2560 f
  ushort* Wf = (ushort*)(wtM + 2560);              // 6144 us
  ushort* wFp = Wf + 6144;                         // 8*8192 us (128 KB)
  float* biasPt = (float*)(wFp + 65536);           // 8*128 f
  float4* partial = (float4*)(biasPt + 1024);      // 64K float4 (1 MB)
  ushort* yA = (ushort*)(partial + 65536);         // 16.78M us
  ushort* yM = yA + (size_t)NB * NC * LL;          // 16.78M us
  ushort* xT = yM + (size_t)NB * NC * LL;          // 16.79M us (incl guards)

  hipLaunchKernelGGL(k_prep, dim3(44), dim3(256), 0, stream,
                     pwAw, pwMw, mw, wtA, wtM, Wf);
  hipLaunchKernelGGL(k_conv, dim3(NB * NGD * 128), dim3(256), 0, stream,
                     x, dwAw, dwAb, dwMw, dwMb, yA, yM, xT, partial);
  hipLaunchKernelGGL(k_fin, dim3(NB), dim3(256), 0, stream,
                     partial, gnAw, gnAb, gnMw, gnMb, wtA, wtM, pwAb, pwMb,
                     wFp, biasPt);
  hipLaunchKernelGGL(k_pd, dim3(NB * 512), dim3(256), 0, stream,
                     yA, yM, xT, wFp, biasPt, Wf, bias, out);
}